// Round 11
// baseline (181.664 us; speedup 1.0000x reference)
//
#include <hip/hip_runtime.h>
#include <stdint.h>

// Head: x[8,2048,1024] fp32; Wk/Wq/Wv [1024,64] fp32 -> out [8,2048,64] fp32
// R16 (resubmit — R10 bench was an acquisition timeout, no data).
// attn reworked for TLP; qkv frozen (six variants all ~40us or worse:
// R4/R13 40.4-40.8, R15 41.0, vmcnt-pipe 52, reg-dbuf 57, direct 76,
// wave-private 80 — invariant to sync/occupancy/tile/traffic; declared done).
// attn was ~35-40us (never in top-5, cutoff 40.7) for 8.6 GFLOP on
// L2-resident K/V — latency-bound at 8 waves/CU (~170 VGPR -> 2 waves/SIMD).
// New attn: 16-row q-tiles, 1024 blocks, 4 waves, same 4-way s-split.
// Live set shrinks (qf/sacc/oacc halve) -> __launch_bounds__(256,4) caps
// VGPR at 128 -> 4 waves/SIMD, 4 blocks/CU = 16 waves/CU (2x hiding).
// K/V logical reads double (L2-served, not binding). LDS 12.9KB.
// wconv + qkv unchanged (R15, measured 41.0).

#define B_ 8
#define T_ 2048
#define C_ 1024
#define H_ 64

typedef float f32x4 __attribute__((ext_vector_type(4)));
typedef short s16x8 __attribute__((ext_vector_type(8)));

__device__ __forceinline__ unsigned int rhu16(float f) {
    return (__float_as_uint(f) + 0x8000u) >> 16;
}
__device__ __forceinline__ unsigned int pkbf(float lo, float hi) {
    unsigned int a = __float_as_uint(lo) + 0x8000u;
    unsigned int b = __float_as_uint(hi) + 0x8000u;
    return __builtin_amdgcn_perm(b, a, 0x07060302u);   // bytes [b3 b2 a3 a2]
}
// async global->LDS, 16B per lane; LDS dest = wave-uniform base + lane*16
__device__ __forceinline__ void ld_lds16(const void* g, void* l) {
    __builtin_amdgcn_global_load_lds(
        (const __attribute__((address_space(1))) unsigned int*)g,
        (__attribute__((address_space(3))) unsigned int*)l, 16, 0, 0);
}

// ---------------------------------------------------------------------------
// K0: 48 blocks = 3 mats x 16 c-groups of 64. Coalesced read, LDS transpose
// (stride 65), coalesced bf16 write. Wq pre-scaled by 1/32 (C^-0.5).
// ---------------------------------------------------------------------------
__global__ __launch_bounds__(256) void wconv(const float* __restrict__ Wk,
        const float* __restrict__ Wq, const float* __restrict__ Wv,
        unsigned short* __restrict__ Wt) {
    __shared__ float ls[64 * 65];
    const int bx = blockIdx.x, t = threadIdx.x;
    const int mat = bx >> 4, c0 = (bx & 15) << 6;
    const float* W = (mat == 0) ? Wk : ((mat == 1) ? Wq : Wv);
    const float sc = (mat == 1) ? 0.03125f : 1.0f;
    #pragma unroll
    for (int k = 0; k < 4; k++) {
        int i = t + (k << 8);
        int cr = i >> 4, hq = (i & 15) << 2;
        float4 v = *reinterpret_cast<const float4*>(&W[(size_t)(c0 + cr) * H_ + hq]);
        ls[cr * 65 + hq + 0] = v.x; ls[cr * 65 + hq + 1] = v.y;
        ls[cr * 65 + hq + 2] = v.z; ls[cr * 65 + hq + 3] = v.w;
    }
    __syncthreads();
    #pragma unroll
    for (int k = 0; k < 4; k++) {
        int i = t + (k << 8);
        int h = i >> 4, cq = (i & 15) << 2;
        float a = ls[(cq + 0) * 65 + h] * sc, b = ls[(cq + 1) * 65 + h] * sc;
        float c = ls[(cq + 2) * 65 + h] * sc, d = ls[(cq + 3) * 65 + h] * sc;
        uint2 o; o.x = pkbf(a, b); o.y = pkbf(c, d);
        *reinterpret_cast<uint2*>(&Wt[(size_t)(mat * 64 + h) * C_ + c0 + cq]) = o;
    }
}

// ---------------------------------------------------------------------------
// K1: QKV projection — 64-row tiles (R15, measured 41.0us). 256 blocks x 512
// thr; block = 64 rows x 192 cols; wave owns 32 rows x 48 cols = acc[2][3].
// Per 64-k chunk per wave: 2 x-stages + 3 W-stages, ds_read frags, pack,
// 12 MFMA, 1 barrier. LDS dbuf 80KB.
// ---------------------------------------------------------------------------
__global__ __launch_bounds__(512) __attribute__((amdgpu_waves_per_eu(2)))
void qkv(const float* __restrict__ x,
        const unsigned short* __restrict__ Wt,
        unsigned short* __restrict__ kb, unsigned short* __restrict__ qb,
        unsigned short* __restrict__ vtb) {
    __shared__ __align__(16) char smem[81920];   // 2 bufs x (16KB x | 24KB W)
    const int t = threadIdx.x, lane = t & 63, w = t >> 6;   // w in 0..7
    const int l15 = lane & 15, quad = lane >> 4;
    const int bx = blockIdx.x;
    const int bb = bx >> 5;                 // batch
    const int mt = bx & 31;                 // 64-row tile within batch
    const int m0 = bb * T_ + mt * 64;
    const int wr = w >> 2;                  // 32-row half of the 64-row tile
    const int colb = (w & 3) * 48;          // 48-col strip

    size_t xg[2]; int xl[2];
    #pragma unroll
    for (int n = 0; n < 2; n++) {
        int id = w * 2 + n, rg = id >> 2, j = id & 3;
        xg[n] = (size_t)(m0 + rg * 16 + l15) * C_ + j * 16 + quad * 4;
        xl[n] = id * 1024 + lane * 16;
    }
    size_t wg[3]; int wl[3];
    #pragma unroll
    for (int n = 0; n < 3; n++) {
        int g = w * 3 + n;
        wg[n] = (size_t)(g * 8 + (lane & 7)) * C_ + (lane >> 3) * 8;
        wl[n] = 16384 + g * 1024 + lane * 16;
    }

    // prologue: stage chunk 0
    #pragma unroll
    for (int n = 0; n < 2; n++) ld_lds16(x + xg[n], smem + xl[n]);
    #pragma unroll
    for (int n = 0; n < 3; n++) ld_lds16(Wt + wg[n], smem + wl[n]);
    __syncthreads();

    f32x4 acc[2][3];
    #pragma unroll
    for (int rt = 0; rt < 2; rt++)
        #pragma unroll
        for (int ct = 0; ct < 3; ct++)
            #pragma unroll
            for (int j = 0; j < 4; j++) acc[rt][ct][j] = 0.0f;

    #pragma unroll
    for (int i = 0; i < 16; i++) {
        const int cb = i & 1;
        const char* cur = smem + cb * 40960;
        const float* xc = (const float*)cur;
        const unsigned short* wcp = (const unsigned short*)(cur + 16384);

        float4 xr[2][2][2];
        #pragma unroll
        for (int rt = 0; rt < 2; rt++)
            #pragma unroll
            for (int ks = 0; ks < 2; ks++)
                #pragma unroll
                for (int h = 0; h < 2; h++) {
                    int c = ks * 32 + quad * 8 + h * 4;
                    int j = c >> 4, u = (c & 15) >> 2;
                    int rg = wr * 2 + rt;
                    xr[rt][ks][h] = *reinterpret_cast<const float4*>(
                        xc + (rg * 4 + j) * 256 + u * 64 + l15 * 4);
                }
        s16x8 wfr[3][2];
        #pragma unroll
        for (int ct = 0; ct < 3; ct++)
            #pragma unroll
            for (int ks = 0; ks < 2; ks++) {
                int col = colb + ct * 16 + l15;
                wfr[ct][ks] = *reinterpret_cast<const s16x8*>(
                    wcp + (col >> 3) * 512 + ((4 * ks + quad) * 8 + (col & 7)) * 8);
            }

        if (i < 15) {
            const int c1 = (i + 1) * 64;
            char* nxt = smem + (cb ^ 1) * 40960;
            #pragma unroll
            for (int n = 0; n < 2; n++) ld_lds16(x + xg[n] + c1, nxt + xl[n]);
            #pragma unroll
            for (int n = 0; n < 3; n++) ld_lds16(Wt + wg[n] + c1, nxt + wl[n]);
        }

        s16x8 af[2][2];
        #pragma unroll
        for (int rt = 0; rt < 2; rt++)
            #pragma unroll
            for (int ks = 0; ks < 2; ks++) {
                const float4 a = xr[rt][ks][0], b = xr[rt][ks][1];
                uint4 pk;
                pk.x = pkbf(a.x, a.y); pk.y = pkbf(a.z, a.w);
                pk.z = pkbf(b.x, b.y); pk.w = pkbf(b.z, b.w);
                af[rt][ks] = *reinterpret_cast<s16x8*>(&pk);
            }
        #pragma unroll
        for (int ks = 0; ks < 2; ks++)
            #pragma unroll
            for (int rt = 0; rt < 2; rt++)
                #pragma unroll
                for (int ct = 0; ct < 3; ct++)
                    acc[rt][ct] = __builtin_amdgcn_mfma_f32_16x16x32_bf16(
                        af[rt][ks], wfr[ct][ks], acc[rt][ct], 0, 0, 0);
        __syncthreads();   // waves' asyncs drained (compiler vmcnt(0)) + swap
    }

    // epilogue: C row = quad*4+reg, col = l15
    #pragma unroll
    for (int ct = 0; ct < 3; ct++) {
        int cbv = colb + ct * 16;
        int sel = cbv >> 6;                 // 0=K 1=Q 2=V, wave-uniform
        int h = (cbv & 63) + l15;
        #pragma unroll
        for (int rt = 0; rt < 2; rt++) {
            int row0 = m0 + (wr * 2 + rt) * 16 + quad * 4;
            if (sel < 2) {
                unsigned short* dst = sel ? qb : kb;
                #pragma unroll
                for (int r = 0; r < 4; r++)
                    dst[(size_t)(row0 + r) * H_ + h] = (unsigned short)rhu16(acc[rt][ct][r]);
            } else {
                int tt = row0 - bb * T_;    // V transposed: 4 consecutive t
                uint2 pk;
                pk.x = pkbf(acc[rt][ct][0], acc[rt][ct][1]);
                pk.y = pkbf(acc[rt][ct][2], acc[rt][ct][3]);
                *reinterpret_cast<uint2*>(&vtb[((size_t)bb * H_ + h) * T_ + tt]) = pk;
            }
        }
    }
}

// ---------------------------------------------------------------------------
// K2: attention — 16-row q-tiles for TLP. 1024 blocks = (batch &7, 16-row
// q-tile), 4 waves; wave owns a 512-s quarter in 8 chunks of 64 s. Per
// iteration: 16 direct register loads, 16 MFMA, 16 exps/lane. VGPR capped
// at 128 via __launch_bounds__(256,4) -> 4 waves/SIMD, 4 blocks/CU.
// LDS: P round-trip (wave-private, stride 72) + 4-way combine epilogue.
// ---------------------------------------------------------------------------
__global__ __launch_bounds__(256, 4) void attn(
        const unsigned short* __restrict__ qb,
        const unsigned short* __restrict__ kb,
        const unsigned short* __restrict__ vtb,
        float* __restrict__ out) {
    __shared__ __align__(16) char smem[12928];
    // main loop: Pw per wave at smem + w*2304 (16 rows x 72 shorts)
    // epilogue (after syncthreads): Osf[3][16][66] f32 (12672B) + Ls[48] f32

    const int t = threadIdx.x, lane = t & 63, w = t >> 6;
    const int l15 = lane & 15, quad = lane >> 4;
    const int bb = blockIdx.x & 7;
    const int q0 = (blockIdx.x >> 3) << 4;
    const size_t kbase = (size_t)bb * T_ * H_;
    unsigned short* Pw = (unsigned short*)(smem + w * 2304);

    // Q B-frags (pre-scaled by 1/32 via Wq), kept in regs for all iterations
    s16x8 qf[2];
    #pragma unroll
    for (int ks = 0; ks < 2; ks++)
        qf[ks] = *reinterpret_cast<const s16x8*>(
            &qb[kbase + (size_t)(q0 + l15) * H_ + ks * 32 + quad * 8]);

    const int sw = w << 9;                 // this wave's s-quarter base
    const unsigned short* kq = kb + kbase + (size_t)(sw + l15) * H_ + quad * 8;
    const unsigned short* vq[4];
    #pragma unroll
    for (int ht = 0; ht < 4; ht++)
        vq[ht] = vtb + ((size_t)bb * H_ + ht * 16 + l15) * T_ + sw + quad * 8;

    f32x4 oacc[4];
    #pragma unroll
    for (int ht = 0; ht < 4; ht++)
        #pragma unroll
        for (int j = 0; j < 4; j++) oacc[ht][j] = 0.0f;
    float l_run = 0.0f;
    const f32x4 z4 = {0.0f, 0.0f, 0.0f, 0.0f};

    for (int it = 0; it < 8; it++) {
        // 16 loads issued back-to-back: 8 K-frags then 8 V-frags. Compiler
        // waits per-use: S-MFMA waits only K; V stays in flight until O-MFMA.
        s16x8 kf[4][2], vf[2][4];
        #pragma unroll
        for (int st = 0; st < 4; st++)
            #pragma unroll
            for (int ks = 0; ks < 2; ks++)
                kf[st][ks] = *reinterpret_cast<const s16x8*>(
                    kq + (size_t)(it * 64 + st * 16) * H_ + ks * 32);
        #pragma unroll
        for (int ks2 = 0; ks2 < 2; ks2++)
            #pragma unroll
            for (int ht = 0; ht < 4; ht++)
                vf[ks2][ht] = *reinterpret_cast<const s16x8*>(
                    vq[ht] + it * 64 + ks2 * 32);

        // S^T = K.Q^T : C row = s (quad*4+r), col = q (l15)
        f32x4 sacc[4];
        #pragma unroll
        for (int st = 0; st < 4; st++) {
            f32x4 s0v = __builtin_amdgcn_mfma_f32_16x16x32_bf16(
                kf[st][0], qf[0], z4, 0, 0, 0);
            sacc[st] = __builtin_amdgcn_mfma_f32_16x16x32_bf16(
                kf[st][1], qf[1], s0v, 0, 0, 0);
        }

        // exp (scores bounded; no max-sub) + packed P write (stride 72)
        {
            float ls = 0.0f;
            #pragma unroll
            for (int st = 0; st < 4; st++) {
                float p0 = __expf(sacc[st][0]);
                float p1 = __expf(sacc[st][1]);
                float p2 = __expf(sacc[st][2]);
                float p3 = __expf(sacc[st][3]);
                ls += (p0 + p1) + (p2 + p3);
                uint2 pk; pk.x = pkbf(p0, p1); pk.y = pkbf(p2, p3);
                *reinterpret_cast<uint2*>(
                    &Pw[l15 * 72 + st * 16 + quad * 4]) = pk;
            }
            l_run += ls;
        }

        // O += P.V : two 32-s k-steps; P read same-wave LDS (lgkmcnt only)
        #pragma unroll
        for (int ks2 = 0; ks2 < 2; ks2++) {
            s16x8 pf = *reinterpret_cast<const s16x8*>(
                &Pw[l15 * 72 + ks2 * 32 + quad * 8]);
            #pragma unroll
            for (int ht = 0; ht < 4; ht++)
                oacc[ht] = __builtin_amdgcn_mfma_f32_16x16x32_bf16(
                    pf, vf[ks2][ht], oacc[ht], 0, 0, 0);
        }
    }

    // l: each lane's partial covers its s-quarter rows for q=l15
    l_run += __shfl_xor(l_run, 16);
    l_run += __shfl_xor(l_run, 32);

    // 4-way split-KV combine (plain sums — no max terms)
    __syncthreads();
    float* Osf = (float*)smem;             // [3][16][66]
    float* Ls  = (float*)smem + 3 * 16 * 66;
    if (w > 0) {
        int wi = w - 1;
        if (quad == 0) Ls[wi * 16 + l15] = l_run;
        #pragma unroll
        for (int ht = 0; ht < 4; ht++)
            #pragma unroll
            for (int r = 0; r < 4; r++)
                Osf[wi * 1056 + (quad * 4 + r) * 66 + ht * 16 + l15] = oacc[ht][r];
    }
    __syncthreads();
    if (w == 0) {
        #pragma unroll
        for (int r = 0; r < 4; r++) {
            int row = quad * 4 + r;
            float lt = __shfl(l_run, row)
                     + Ls[0 * 16 + row] + Ls[1 * 16 + row] + Ls[2 * 16 + row];
            float inv = 1.0f / lt;
            #pragma unroll
            for (int ht = 0; ht < 4; ht++) {
                float o = oacc[ht][r]
                        + Osf[0 * 1056 + row * 66 + ht * 16 + l15]
                        + Osf[1 * 1056 + row * 66 + ht * 16 + l15]
                        + Osf[2 * 1056 + row * 66 + ht * 16 + l15];
                out[kbase + (size_t)(q0 + row) * H_ + ht * 16 + l15] = o * inv;
            }
        }
    }
}

extern "C" void kernel_launch(void* const* d_in, const int* in_sizes, int n_in,
                              void* d_out, int out_size, void* d_ws, size_t ws_size,
                              hipStream_t stream) {
    const float* x  = (const float*)d_in[0];
    const float* Wk = (const float*)d_in[1];
    const float* Wq = (const float*)d_in[2];
    const float* Wv = (const float*)d_in[3];

    unsigned short* kb  = (unsigned short*)d_ws;               // 2 MB
    unsigned short* qbf = kb  + (size_t)B_ * T_ * H_;          // 2 MB
    unsigned short* vtb = qbf + (size_t)B_ * T_ * H_;          // 2 MB
    unsigned short* Wt  = (unsigned short*)d_out;              // 384 KB scratch

    wconv<<<48,   256, 0, stream>>>(Wk, Wq, Wv, Wt);
    qkv  <<<256,  512, 0, stream>>>(x, Wt, kb, qbf, vtb);
    attn <<<1024, 256, 0, stream>>>(qbf, kb, vtb, (float*)d_out);
}

// Round 12
// 153.959 us; speedup vs baseline: 1.1800x; 1.1800x over previous
//
#include <hip/hip_runtime.h>
#include <stdint.h>

// Head: x[8,2048,1024] fp32; Wk/Wq/Wv [1024,64] fp32 -> out [8,2048,64] fp32
// R17: revert to proven-best config (R13 qkv 40.4us + R9 attn, total 151.997)
// + two low-risk attn micro-levers. R16 post-mortem: 16-row q-tiles DOUBLED
// total K/V loads (loads/block are q-height-independent) and launch_bounds
// (256,4) re-triggered the VGPR squeeze (56 regs -> serialized loads) ->
// 63us. attn is load-bound; keep 32-row geometry and add: (a) #pragma
// unroll 2 on the barrier-free it-loop so iter i+1's 16 loads hoist into
// iter i's compute (VGPR cap 256 has room: ~170+64); (b) s_setprio(1)
// around MFMA clusters — independent non-barrier blocks = the regime where
// setprio measured +4-7% on attn (m191). qkv = R13 verbatim; wconv same.

#define B_ 8
#define T_ 2048
#define C_ 1024
#define H_ 64

typedef float f32x4 __attribute__((ext_vector_type(4)));
typedef short s16x8 __attribute__((ext_vector_type(8)));

__device__ __forceinline__ unsigned int rhu16(float f) {
    return (__float_as_uint(f) + 0x8000u) >> 16;
}
__device__ __forceinline__ unsigned int pkbf(float lo, float hi) {
    unsigned int a = __float_as_uint(lo) + 0x8000u;
    unsigned int b = __float_as_uint(hi) + 0x8000u;
    return __builtin_amdgcn_perm(b, a, 0x07060302u);   // bytes [b3 b2 a3 a2]
}
// async global->LDS, 16B per lane; LDS dest = wave-uniform base + lane*16
__device__ __forceinline__ void ld_lds16(const void* g, void* l) {
    __builtin_amdgcn_global_load_lds(
        (const __attribute__((address_space(1))) unsigned int*)g,
        (__attribute__((address_space(3))) unsigned int*)l, 16, 0, 0);
}

// ---------------------------------------------------------------------------
// K0: 48 blocks = 3 mats x 16 c-groups of 64. Coalesced read, LDS transpose
// (stride 65), coalesced bf16 write. Wq pre-scaled by 1/32 (C^-0.5).
// ---------------------------------------------------------------------------
__global__ __launch_bounds__(256) void wconv(const float* __restrict__ Wk,
        const float* __restrict__ Wq, const float* __restrict__ Wv,
        unsigned short* __restrict__ Wt) {
    __shared__ float ls[64 * 65];
    const int bx = blockIdx.x, t = threadIdx.x;
    const int mat = bx >> 4, c0 = (bx & 15) << 6;
    const float* W = (mat == 0) ? Wk : ((mat == 1) ? Wq : Wv);
    const float sc = (mat == 1) ? 0.03125f : 1.0f;
    #pragma unroll
    for (int k = 0; k < 4; k++) {
        int i = t + (k << 8);
        int cr = i >> 4, hq = (i & 15) << 2;
        float4 v = *reinterpret_cast<const float4*>(&W[(size_t)(c0 + cr) * H_ + hq]);
        ls[cr * 65 + hq + 0] = v.x; ls[cr * 65 + hq + 1] = v.y;
        ls[cr * 65 + hq + 2] = v.z; ls[cr * 65 + hq + 3] = v.w;
    }
    __syncthreads();
    #pragma unroll
    for (int k = 0; k < 4; k++) {
        int i = t + (k << 8);
        int h = i >> 4, cq = (i & 15) << 2;
        float a = ls[(cq + 0) * 65 + h] * sc, b = ls[(cq + 1) * 65 + h] * sc;
        float c = ls[(cq + 2) * 65 + h] * sc, d = ls[(cq + 3) * 65 + h] * sc;
        uint2 o; o.x = pkbf(a, b); o.y = pkbf(c, d);
        *reinterpret_cast<uint2*>(&Wt[(size_t)(mat * 64 + h) * C_ + c0 + cq]) = o;
    }
}

// ---------------------------------------------------------------------------
// K1: QKV projection — R13 verbatim (best measured, 40.4us). 512 blocks x
// 512 thr; block = 32 rows x 192 cols; wave (wr=w>>2, colb=(w&3)*48) owns
// 16 rows x 48 cols. Per 64-k chunk per wave: 1 x-stage + 3 W-stages,
// ds_read frags, pack, 6 MFMA, 1 barrier. LDS dbuf 64KB.
// ---------------------------------------------------------------------------
__global__ __launch_bounds__(512) __attribute__((amdgpu_waves_per_eu(4, 4)))
void qkv(const float* __restrict__ x,
        const unsigned short* __restrict__ Wt,
        unsigned short* __restrict__ kb, unsigned short* __restrict__ qb,
        unsigned short* __restrict__ vtb) {
    __shared__ __align__(16) char smem[65536];   // xbuf 2x8192 | wbuf 2x24576
    char* xb = smem;
    char* wb = smem + 16384;

    const int t = threadIdx.x, lane = t & 63, w = t >> 6;   // w in 0..7
    const int l15 = lane & 15, quad = lane >> 4;
    const int bx = blockIdx.x;
    const int bb = bx >> 6;                 // batch
    const int mt = bx & 63;                 // 32-row tile within batch
    const int m0 = bb * T_ + mt * 32;
    const int wr = w >> 2;                  // row-half of the 32-row tile
    const int colb = (w & 3) * 48;          // 48-col strip

    size_t xg; int xl;
    {
        int rg = w >> 2, j = w & 3;
        xg = (size_t)(m0 + rg * 16 + l15) * C_ + j * 16 + quad * 4;
        xl = w * 1024 + lane * 16;
    }
    size_t wg[3]; int wl[3];
    #pragma unroll
    for (int n = 0; n < 3; n++) {
        int g = w * 3 + n;
        wg[n] = (size_t)(g * 8 + (lane & 7)) * C_ + (lane >> 3) * 8;
        wl[n] = g * 1024 + lane * 16;
    }

    // prologue: stage chunk 0
    ld_lds16(x + xg, xb + xl);
    #pragma unroll
    for (int n = 0; n < 3; n++) ld_lds16(Wt + wg[n], wb + wl[n]);
    __syncthreads();

    f32x4 acc[3];
    #pragma unroll
    for (int ct = 0; ct < 3; ct++)
        #pragma unroll
        for (int j = 0; j < 4; j++) acc[ct][j] = 0.0f;

    #pragma unroll
    for (int i = 0; i < 16; i++) {
        const int cb = i & 1;
        const float* xc = (const float*)(xb + cb * 8192);
        const unsigned short* wcp = (const unsigned short*)(wb + cb * 24576);

        float4 xr[2][2];
        #pragma unroll
        for (int ks = 0; ks < 2; ks++)
            #pragma unroll
            for (int h = 0; h < 2; h++) {
                int c = ks * 32 + quad * 8 + h * 4;
                int j = c >> 4, u = (c & 15) >> 2;
                xr[ks][h] = *reinterpret_cast<const float4*>(
                    xc + (wr * 4 + j) * 256 + u * 64 + l15 * 4);
            }
        s16x8 wfr[3][2];
        #pragma unroll
        for (int ct = 0; ct < 3; ct++)
            #pragma unroll
            for (int ks = 0; ks < 2; ks++) {
                int col = colb + ct * 16 + l15;
                wfr[ct][ks] = *reinterpret_cast<const s16x8*>(
                    wcp + (col >> 3) * 512 + ((4 * ks + quad) * 8 + (col & 7)) * 8);
            }

        if (i < 15) {
            const int c1 = (i + 1) * 64;
            char* xn = xb + (cb ^ 1) * 8192;
            char* wn = wb + (cb ^ 1) * 24576;
            ld_lds16(x + xg + c1, xn + xl);
            #pragma unroll
            for (int n = 0; n < 3; n++) ld_lds16(Wt + wg[n] + c1, wn + wl[n]);
        }

        s16x8 af[2];
        #pragma unroll
        for (int ks = 0; ks < 2; ks++) {
            const float4 a = xr[ks][0], b = xr[ks][1];
            uint4 pk;
            pk.x = pkbf(a.x, a.y); pk.y = pkbf(a.z, a.w);
            pk.z = pkbf(b.x, b.y); pk.w = pkbf(b.z, b.w);
            af[ks] = *reinterpret_cast<s16x8*>(&pk);
        }
        #pragma unroll
        for (int ks = 0; ks < 2; ks++)
            #pragma unroll
            for (int ct = 0; ct < 3; ct++)
                acc[ct] = __builtin_amdgcn_mfma_f32_16x16x32_bf16(
                    af[ks], wfr[ct][ks], acc[ct], 0, 0, 0);
        __syncthreads();   // waves' asyncs drained (compiler vmcnt(0)) + swap
    }

    // epilogue: C row = quad*4+reg (within wave's 16-row strip), col = l15
    #pragma unroll
    for (int ct = 0; ct < 3; ct++) {
        int cbv = colb + ct * 16;
        int sel = cbv >> 6;                 // 0=K 1=Q 2=V, wave-uniform
        int h = (cbv & 63) + l15;
        int row0 = m0 + wr * 16 + quad * 4;
        if (sel < 2) {
            unsigned short* dst = sel ? qb : kb;
            #pragma unroll
            for (int r = 0; r < 4; r++)
                dst[(size_t)(row0 + r) * H_ + h] = (unsigned short)rhu16(acc[ct][r]);
        } else {
            int tt = row0 - bb * T_;        // V transposed: 4 consecutive t
            uint2 pk;
            pk.x = pkbf(acc[ct][0], acc[ct][1]);
            pk.y = pkbf(acc[ct][2], acc[ct][3]);
            *reinterpret_cast<uint2*>(&vtb[((size_t)bb * H_ + h) * T_ + tt]) = pk;
        }
    }
}

// ---------------------------------------------------------------------------
// K2: attention — R9 geometry (proven in 151.997 best) + unroll-2 + setprio.
// 512 blocks = (batch &7, 32-row q-tile), 4 waves; wave owns a 512-s
// quarter in 8 chunks of 64 s. No barriers in main loop -> unroll 2 lets
// the compiler hoist next iter's 16 loads into current compute; setprio
// favors MFMA-entering waves (independent-block regime).
// ---------------------------------------------------------------------------
__global__ __launch_bounds__(256, 2) void attn(
        const unsigned short* __restrict__ qb,
        const unsigned short* __restrict__ kb,
        const unsigned short* __restrict__ vtb,
        float* __restrict__ out) {
    __shared__ __align__(16) char smem[25728];
    // main loop: Pw per wave at smem + w*4608 (32 rows x 72 shorts)
    // epilogue (after syncthreads): Osf[3][32][66] f32 (25344B) + Ls[96] f32

    const int t = threadIdx.x, lane = t & 63, w = t >> 6;
    const int l15 = lane & 15, quad = lane >> 4;
    const int bb = blockIdx.x & 7;
    const int q0 = (blockIdx.x >> 3) << 5;
    const size_t kbase = (size_t)bb * T_ * H_;
    unsigned short* Pw = (unsigned short*)(smem + w * 4608);

    // Q B-frags (pre-scaled by 1/32 via Wq), kept in regs for all iterations
    s16x8 qf[2][2];
    #pragma unroll
    for (int rt = 0; rt < 2; rt++)
        #pragma unroll
        for (int ks = 0; ks < 2; ks++)
            qf[rt][ks] = *reinterpret_cast<const s16x8*>(
                &qb[kbase + (size_t)(q0 + rt * 16 + l15) * H_ + ks * 32 + quad * 8]);

    const int sw = w << 9;                 // this wave's s-quarter base
    const unsigned short* kq = kb + kbase + (size_t)(sw + l15) * H_ + quad * 8;
    const unsigned short* vq[4];
    #pragma unroll
    for (int ht = 0; ht < 4; ht++)
        vq[ht] = vtb + ((size_t)bb * H_ + ht * 16 + l15) * T_ + sw + quad * 8;

    f32x4 oacc[2][4];
    #pragma unroll
    for (int rt = 0; rt < 2; rt++)
        #pragma unroll
        for (int ht = 0; ht < 4; ht++)
            #pragma unroll
            for (int j = 0; j < 4; j++) oacc[rt][ht][j] = 0.0f;
    float l_run[2] = {0.0f, 0.0f};
    const f32x4 z4 = {0.0f, 0.0f, 0.0f, 0.0f};

    #pragma unroll 2
    for (int it = 0; it < 8; it++) {
        // 16 loads issued back-to-back: 8 K-frags then 8 V-frags. Compiler
        // waits per-use: S-MFMA waits only K; V stays in flight until O-MFMA.
        s16x8 kf[4][2], vf[2][4];
        #pragma unroll
        for (int st = 0; st < 4; st++)
            #pragma unroll
            for (int ks = 0; ks < 2; ks++)
                kf[st][ks] = *reinterpret_cast<const s16x8*>(
                    kq + (size_t)(it * 64 + st * 16) * H_ + ks * 32);
        #pragma unroll
        for (int ks2 = 0; ks2 < 2; ks2++)
            #pragma unroll
            for (int ht = 0; ht < 4; ht++)
                vf[ks2][ht] = *reinterpret_cast<const s16x8*>(
                    vq[ht] + it * 64 + ks2 * 32);

        // S^T = K.Q^T : C row = s (quad*4+r), col = q (l15)
        f32x4 sacc[2][4];
        __builtin_amdgcn_s_setprio(1);
        #pragma unroll
        for (int rt = 0; rt < 2; rt++)
            #pragma unroll
            for (int st = 0; st < 4; st++) {
                f32x4 s0v = __builtin_amdgcn_mfma_f32_16x16x32_bf16(
                    kf[st][0], qf[rt][0], z4, 0, 0, 0);
                sacc[rt][st] = __builtin_amdgcn_mfma_f32_16x16x32_bf16(
                    kf[st][1], qf[rt][1], s0v, 0, 0, 0);
            }
        __builtin_amdgcn_s_setprio(0);

        // exp (scores bounded; no max-sub) + packed P write (stride 72)
        #pragma unroll
        for (int rt = 0; rt < 2; rt++) {
            float ls = 0.0f;
            #pragma unroll
            for (int st = 0; st < 4; st++) {
                float p0 = __expf(sacc[rt][st][0]);
                float p1 = __expf(sacc[rt][st][1]);
                float p2 = __expf(sacc[rt][st][2]);
                float p3 = __expf(sacc[rt][st][3]);
                ls += (p0 + p1) + (p2 + p3);
                uint2 pk; pk.x = pkbf(p0, p1); pk.y = pkbf(p2, p3);
                *reinterpret_cast<uint2*>(
                    &Pw[(rt * 16 + l15) * 72 + st * 16 + quad * 4]) = pk;
            }
            l_run[rt] += ls;
        }

        // O += P.V : two 32-s k-steps; P read same-wave LDS (lgkmcnt only)
        __builtin_amdgcn_s_setprio(1);
        #pragma unroll
        for (int rt = 0; rt < 2; rt++)
            #pragma unroll
            for (int ks2 = 0; ks2 < 2; ks2++) {
                s16x8 pf = *reinterpret_cast<const s16x8*>(
                    &Pw[(rt * 16 + l15) * 72 + ks2 * 32 + quad * 8]);
                #pragma unroll
                for (int ht = 0; ht < 4; ht++)
                    oacc[rt][ht] = __builtin_amdgcn_mfma_f32_16x16x32_bf16(
                        pf, vf[ks2][ht], oacc[rt][ht], 0, 0, 0);
            }
        __builtin_amdgcn_s_setprio(0);
    }

    // l: each lane's partial covers its s-quarter rows for q=l15
    #pragma unroll
    for (int rt = 0; rt < 2; rt++) {
        l_run[rt] += __shfl_xor(l_run[rt], 16);
        l_run[rt] += __shfl_xor(l_run[rt], 32);
    }

    // 4-way split-KV combine (plain sums — no max terms)
    __syncthreads();
    float* Osf = (float*)smem;             // [3][32][66]
    float* Ls  = (float*)smem + 3 * 32 * 66;
    if (w > 0) {
        int wi = w - 1;
        #pragma unroll
        for (int rt = 0; rt < 2; rt++) {
            if (quad == 0) Ls[wi * 32 + rt * 16 + l15] = l_run[rt];
            #pragma unroll
            for (int ht = 0; ht < 4; ht++)
                #pragma unroll
                for (int r = 0; r < 4; r++)
                    Osf[wi * 2112 + (rt * 16 + quad * 4 + r) * 66 + ht * 16 + l15] = oacc[rt][ht][r];
        }
    }
    __syncthreads();
    if (w == 0) {
        #pragma unroll
        for (int rt = 0; rt < 2; rt++)
            #pragma unroll
            for (int r = 0; r < 4; r++) {
                int row = rt * 16 + quad * 4 + r;
                float lt = __shfl(l_run[rt], quad * 4 + r)
                         + Ls[0 * 32 + row] + Ls[1 * 32 + row] + Ls[2 * 32 + row];
                float inv = 1.0f / lt;
                #pragma unroll
                for (int ht = 0; ht < 4; ht++) {
                    float o = oacc[rt][ht][r]
                            + Osf[0 * 2112 + row * 66 + ht * 16 + l15]
                            + Osf[1 * 2112 + row * 66 + ht * 16 + l15]
                            + Osf[2 * 2112 + row * 66 + ht * 16 + l15];
                    out[kbase + (size_t)(q0 + row) * H_ + ht * 16 + l15] = o * inv;
                }
            }
    }
}

extern "C" void kernel_launch(void* const* d_in, const int* in_sizes, int n_in,
                              void* d_out, int out_size, void* d_ws, size_t ws_size,
                              hipStream_t stream) {
    const float* x  = (const float*)d_in[0];
    const float* Wk = (const float*)d_in[1];
    const float* Wq = (const float*)d_in[2];
    const float* Wv = (const float*)d_in[3];

    unsigned short* kb  = (unsigned short*)d_ws;               // 2 MB
    unsigned short* qbf = kb  + (size_t)B_ * T_ * H_;          // 2 MB
    unsigned short* vtb = qbf + (size_t)B_ * T_ * H_;          // 2 MB
    unsigned short* Wt  = (unsigned short*)d_out;              // 384 KB scratch

    wconv<<<48,  256, 0, stream>>>(Wk, Wq, Wv, Wt);
    qkv  <<<512, 512, 0, stream>>>(x, Wt, kb, qbf, vtb);
    attn <<<512, 256, 0, stream>>>(qbf, kb, vtb, (float*)d_out);
}

// Round 14
// 142.560 us; speedup vs baseline: 1.2743x; 1.0800x over previous
//
#include <hip/hip_runtime.h>
#include <stdint.h>

// Head: x[8,2048,1024] fp32; Wk/Wq/Wv [1024,64] fp32 -> out [8,2048,64] fp32
// R18 (resubmit — R13 bench was an acquisition timeout, no data).
// attn 64-row q-tiles. R16 proved K/V loads/block are q-height-
// independent (each block reads its batch's full 512KB K+V): 2x blocks ->
// 2x loads -> 36->63us. Inverting: 256 blocks x 8 waves (512 thr), each
// wave owns a 256-s eighth (4 iters x 64 s) -> total load instrs HALVE at
// IDENTICAL occupancy (8 waves/CU = 2/SIMD before and after). VGPR ~210
// fits waves_per_eu(2,2)'s 256 cap (no R16 squeeze); sacc per-rt keeps
// transients at 16. Epilogue: all-8-wave LDS combine (Osf[8][64][66],
// 135KB — 134KB total static LDS < 160KB/CU). R17's unroll2+setprio
// measured neutral (153.96 vs 152.00) — dropped. qkv = R13 verbatim
// (40.4us); wconv unchanged.

#define B_ 8
#define T_ 2048
#define C_ 1024
#define H_ 64

typedef float f32x4 __attribute__((ext_vector_type(4)));
typedef short s16x8 __attribute__((ext_vector_type(8)));

__device__ __forceinline__ unsigned int rhu16(float f) {
    return (__float_as_uint(f) + 0x8000u) >> 16;
}
__device__ __forceinline__ unsigned int pkbf(float lo, float hi) {
    unsigned int a = __float_as_uint(lo) + 0x8000u;
    unsigned int b = __float_as_uint(hi) + 0x8000u;
    return __builtin_amdgcn_perm(b, a, 0x07060302u);   // bytes [b3 b2 a3 a2]
}
// async global->LDS, 16B per lane; LDS dest = wave-uniform base + lane*16
__device__ __forceinline__ void ld_lds16(const void* g, void* l) {
    __builtin_amdgcn_global_load_lds(
        (const __attribute__((address_space(1))) unsigned int*)g,
        (__attribute__((address_space(3))) unsigned int*)l, 16, 0, 0);
}

// ---------------------------------------------------------------------------
// K0: 48 blocks = 3 mats x 16 c-groups of 64. Coalesced read, LDS transpose
// (stride 65), coalesced bf16 write. Wq pre-scaled by 1/32 (C^-0.5).
// ---------------------------------------------------------------------------
__global__ __launch_bounds__(256) void wconv(const float* __restrict__ Wk,
        const float* __restrict__ Wq, const float* __restrict__ Wv,
        unsigned short* __restrict__ Wt) {
    __shared__ float ls[64 * 65];
    const int bx = blockIdx.x, t = threadIdx.x;
    const int mat = bx >> 4, c0 = (bx & 15) << 6;
    const float* W = (mat == 0) ? Wk : ((mat == 1) ? Wq : Wv);
    const float sc = (mat == 1) ? 0.03125f : 1.0f;
    #pragma unroll
    for (int k = 0; k < 4; k++) {
        int i = t + (k << 8);
        int cr = i >> 4, hq = (i & 15) << 2;
        float4 v = *reinterpret_cast<const float4*>(&W[(size_t)(c0 + cr) * H_ + hq]);
        ls[cr * 65 + hq + 0] = v.x; ls[cr * 65 + hq + 1] = v.y;
        ls[cr * 65 + hq + 2] = v.z; ls[cr * 65 + hq + 3] = v.w;
    }
    __syncthreads();
    #pragma unroll
    for (int k = 0; k < 4; k++) {
        int i = t + (k << 8);
        int h = i >> 4, cq = (i & 15) << 2;
        float a = ls[(cq + 0) * 65 + h] * sc, b = ls[(cq + 1) * 65 + h] * sc;
        float c = ls[(cq + 2) * 65 + h] * sc, d = ls[(cq + 3) * 65 + h] * sc;
        uint2 o; o.x = pkbf(a, b); o.y = pkbf(c, d);
        *reinterpret_cast<uint2*>(&Wt[(size_t)(mat * 64 + h) * C_ + c0 + cq]) = o;
    }
}

// ---------------------------------------------------------------------------
// K1: QKV projection — R13 verbatim (best measured, 40.4us). 512 blocks x
// 512 thr; block = 32 rows x 192 cols; wave (wr=w>>2, colb=(w&3)*48) owns
// 16 rows x 48 cols. Per 64-k chunk per wave: 1 x-stage + 3 W-stages,
// ds_read frags, pack, 6 MFMA, 1 barrier. LDS dbuf 64KB.
// ---------------------------------------------------------------------------
__global__ __launch_bounds__(512) __attribute__((amdgpu_waves_per_eu(4, 4)))
void qkv(const float* __restrict__ x,
        const unsigned short* __restrict__ Wt,
        unsigned short* __restrict__ kb, unsigned short* __restrict__ qb,
        unsigned short* __restrict__ vtb) {
    __shared__ __align__(16) char smem[65536];   // xbuf 2x8192 | wbuf 2x24576
    char* xb = smem;
    char* wb = smem + 16384;

    const int t = threadIdx.x, lane = t & 63, w = t >> 6;   // w in 0..7
    const int l15 = lane & 15, quad = lane >> 4;
    const int bx = blockIdx.x;
    const int bb = bx >> 6;                 // batch
    const int mt = bx & 63;                 // 32-row tile within batch
    const int m0 = bb * T_ + mt * 32;
    const int wr = w >> 2;                  // row-half of the 32-row tile
    const int colb = (w & 3) * 48;          // 48-col strip

    size_t xg; int xl;
    {
        int rg = w >> 2, j = w & 3;
        xg = (size_t)(m0 + rg * 16 + l15) * C_ + j * 16 + quad * 4;
        xl = w * 1024 + lane * 16;
    }
    size_t wg[3]; int wl[3];
    #pragma unroll
    for (int n = 0; n < 3; n++) {
        int g = w * 3 + n;
        wg[n] = (size_t)(g * 8 + (lane & 7)) * C_ + (lane >> 3) * 8;
        wl[n] = g * 1024 + lane * 16;
    }

    // prologue: stage chunk 0
    ld_lds16(x + xg, xb + xl);
    #pragma unroll
    for (int n = 0; n < 3; n++) ld_lds16(Wt + wg[n], wb + wl[n]);
    __syncthreads();

    f32x4 acc[3];
    #pragma unroll
    for (int ct = 0; ct < 3; ct++)
        #pragma unroll
        for (int j = 0; j < 4; j++) acc[ct][j] = 0.0f;

    #pragma unroll
    for (int i = 0; i < 16; i++) {
        const int cb = i & 1;
        const float* xc = (const float*)(xb + cb * 8192);
        const unsigned short* wcp = (const unsigned short*)(wb + cb * 24576);

        float4 xr[2][2];
        #pragma unroll
        for (int ks = 0; ks < 2; ks++)
            #pragma unroll
            for (int h = 0; h < 2; h++) {
                int c = ks * 32 + quad * 8 + h * 4;
                int j = c >> 4, u = (c & 15) >> 2;
                xr[ks][h] = *reinterpret_cast<const float4*>(
                    xc + (wr * 4 + j) * 256 + u * 64 + l15 * 4);
            }
        s16x8 wfr[3][2];
        #pragma unroll
        for (int ct = 0; ct < 3; ct++)
            #pragma unroll
            for (int ks = 0; ks < 2; ks++) {
                int col = colb + ct * 16 + l15;
                wfr[ct][ks] = *reinterpret_cast<const s16x8*>(
                    wcp + (col >> 3) * 512 + ((4 * ks + quad) * 8 + (col & 7)) * 8);
            }

        if (i < 15) {
            const int c1 = (i + 1) * 64;
            char* xn = xb + (cb ^ 1) * 8192;
            char* wn = wb + (cb ^ 1) * 24576;
            ld_lds16(x + xg + c1, xn + xl);
            #pragma unroll
            for (int n = 0; n < 3; n++) ld_lds16(Wt + wg[n] + c1, wn + wl[n]);
        }

        s16x8 af[2];
        #pragma unroll
        for (int ks = 0; ks < 2; ks++) {
            const float4 a = xr[ks][0], b = xr[ks][1];
            uint4 pk;
            pk.x = pkbf(a.x, a.y); pk.y = pkbf(a.z, a.w);
            pk.z = pkbf(b.x, b.y); pk.w = pkbf(b.z, b.w);
            af[ks] = *reinterpret_cast<s16x8*>(&pk);
        }
        #pragma unroll
        for (int ks = 0; ks < 2; ks++)
            #pragma unroll
            for (int ct = 0; ct < 3; ct++)
                acc[ct] = __builtin_amdgcn_mfma_f32_16x16x32_bf16(
                    af[ks], wfr[ct][ks], acc[ct], 0, 0, 0);
        __syncthreads();   // waves' asyncs drained (compiler vmcnt(0)) + swap
    }

    // epilogue: C row = quad*4+reg (within wave's 16-row strip), col = l15
    #pragma unroll
    for (int ct = 0; ct < 3; ct++) {
        int cbv = colb + ct * 16;
        int sel = cbv >> 6;                 // 0=K 1=Q 2=V, wave-uniform
        int h = (cbv & 63) + l15;
        int row0 = m0 + wr * 16 + quad * 4;
        if (sel < 2) {
            unsigned short* dst = sel ? qb : kb;
            #pragma unroll
            for (int r = 0; r < 4; r++)
                dst[(size_t)(row0 + r) * H_ + h] = (unsigned short)rhu16(acc[ct][r]);
        } else {
            int tt = row0 - bb * T_;        // V transposed: 4 consecutive t
            uint2 pk;
            pk.x = pkbf(acc[ct][0], acc[ct][1]);
            pk.y = pkbf(acc[ct][2], acc[ct][3]);
            *reinterpret_cast<uint2*>(&vtb[((size_t)bb * H_ + h) * T_ + tt]) = pk;
        }
    }
}

// ---------------------------------------------------------------------------
// K2: attention — 64-row q-tiles, 8 waves. 256 blocks = (batch &7, 64-row
// q-tile); wave owns a 256-s eighth in 4 chunks of 64 s. Per iteration:
// 16 direct register loads (half the old total), 64 MFMA, 64 exps/lane
// (per-rt sacc keeps transients at 16 VGPR). LDS: Pw per wave (64 rows x
// 72 shorts) in main loop; all-8-wave combine epilogue (Osf[8][64][66]).
// ---------------------------------------------------------------------------
__global__ __launch_bounds__(512) __attribute__((amdgpu_waves_per_eu(2, 2)))
void attn(
        const unsigned short* __restrict__ qb,
        const unsigned short* __restrict__ kb,
        const unsigned short* __restrict__ vtb,
        float* __restrict__ out) {
    __shared__ __align__(16) char smem[137216];
    // main loop: Pw per wave at smem + w*9216 (64 rows x 72 shorts = 73728B)
    // epilogue (after syncthreads): Osf[8][64][66] f32 (135168B) + Ls[8][64]

    const int t = threadIdx.x, lane = t & 63, w = t >> 6;   // w in 0..7
    const int l15 = lane & 15, quad = lane >> 4;
    const int bb = blockIdx.x & 7;
    const int q0 = (blockIdx.x >> 3) << 6;  // 64-row q tile
    const size_t kbase = (size_t)bb * T_ * H_;
    unsigned short* Pw = (unsigned short*)(smem + w * 9216);

    // Q B-frags (pre-scaled by 1/32 via Wq), kept in regs for all iterations
    s16x8 qf[4][2];
    #pragma unroll
    for (int rt = 0; rt < 4; rt++)
        #pragma unroll
        for (int ks = 0; ks < 2; ks++)
            qf[rt][ks] = *reinterpret_cast<const s16x8*>(
                &qb[kbase + (size_t)(q0 + rt * 16 + l15) * H_ + ks * 32 + quad * 8]);

    const int sw = w << 8;                 // this wave's 256-s eighth base
    const unsigned short* kq = kb + kbase + (size_t)(sw + l15) * H_ + quad * 8;
    const unsigned short* vq[4];
    #pragma unroll
    for (int ht = 0; ht < 4; ht++)
        vq[ht] = vtb + ((size_t)bb * H_ + ht * 16 + l15) * T_ + sw + quad * 8;

    f32x4 oacc[4][4];
    #pragma unroll
    for (int rt = 0; rt < 4; rt++)
        #pragma unroll
        for (int ht = 0; ht < 4; ht++)
            #pragma unroll
            for (int j = 0; j < 4; j++) oacc[rt][ht][j] = 0.0f;
    float l_run[4] = {0.0f, 0.0f, 0.0f, 0.0f};
    const f32x4 z4 = {0.0f, 0.0f, 0.0f, 0.0f};

    for (int it = 0; it < 4; it++) {
        // 16 loads issued back-to-back: 8 K-frags then 8 V-frags. Compiler
        // waits per-use: S-MFMA waits only K; V stays in flight until O-MFMA.
        s16x8 kf[4][2], vf[2][4];
        #pragma unroll
        for (int st = 0; st < 4; st++)
            #pragma unroll
            for (int ks = 0; ks < 2; ks++)
                kf[st][ks] = *reinterpret_cast<const s16x8*>(
                    kq + (size_t)(it * 64 + st * 16) * H_ + ks * 32);
        #pragma unroll
        for (int ks2 = 0; ks2 < 2; ks2++)
            #pragma unroll
            for (int ht = 0; ht < 4; ht++)
                vf[ks2][ht] = *reinterpret_cast<const s16x8*>(
                    vq[ht] + it * 64 + ks2 * 32);

        // S^T = K.Q^T per 16-q group rt (sacc transient: 16 VGPR), then
        // exp (scores bounded; no max-sub) + packed P write (stride 72)
        #pragma unroll
        for (int rt = 0; rt < 4; rt++) {
            f32x4 sacc[4];
            #pragma unroll
            for (int st = 0; st < 4; st++) {
                f32x4 s0v = __builtin_amdgcn_mfma_f32_16x16x32_bf16(
                    kf[st][0], qf[rt][0], z4, 0, 0, 0);
                sacc[st] = __builtin_amdgcn_mfma_f32_16x16x32_bf16(
                    kf[st][1], qf[rt][1], s0v, 0, 0, 0);
            }
            float ls = 0.0f;
            #pragma unroll
            for (int st = 0; st < 4; st++) {
                float p0 = __expf(sacc[st][0]);
                float p1 = __expf(sacc[st][1]);
                float p2 = __expf(sacc[st][2]);
                float p3 = __expf(sacc[st][3]);
                ls += (p0 + p1) + (p2 + p3);
                uint2 pk; pk.x = pkbf(p0, p1); pk.y = pkbf(p2, p3);
                *reinterpret_cast<uint2*>(
                    &Pw[(rt * 16 + l15) * 72 + st * 16 + quad * 4]) = pk;
            }
            l_run[rt] += ls;
        }

        // O += P.V : two 32-s k-steps; P read same-wave LDS (lgkmcnt only)
        #pragma unroll
        for (int rt = 0; rt < 4; rt++)
            #pragma unroll
            for (int ks2 = 0; ks2 < 2; ks2++) {
                s16x8 pf = *reinterpret_cast<const s16x8*>(
                    &Pw[(rt * 16 + l15) * 72 + ks2 * 32 + quad * 8]);
                #pragma unroll
                for (int ht = 0; ht < 4; ht++)
                    oacc[rt][ht] = __builtin_amdgcn_mfma_f32_16x16x32_bf16(
                        pf, vf[ks2][ht], oacc[rt][ht], 0, 0, 0);
            }
    }

    // l: each lane's partial covers its s-eighth rows for q=l15
    #pragma unroll
    for (int rt = 0; rt < 4; rt++) {
        l_run[rt] += __shfl_xor(l_run[rt], 16);
        l_run[rt] += __shfl_xor(l_run[rt], 32);
    }

    // 8-way split-KV combine: ALL waves write partials, then each wave
    // combines 8 rows (lane = h, coalesced output).
    __syncthreads();                       // Pw reads done; safe to overwrite
    float* Osf = (float*)smem;             // [8][64][66]
    float* Ls  = (float*)smem + 8 * 64 * 66;   // [8][64]
    #pragma unroll
    for (int rt = 0; rt < 4; rt++) {
        if (quad == 0) Ls[w * 64 + rt * 16 + l15] = l_run[rt];
        #pragma unroll
        for (int ht = 0; ht < 4; ht++)
            #pragma unroll
            for (int r = 0; r < 4; r++)
                Osf[(w * 64 + rt * 16 + quad * 4 + r) * 66 + ht * 16 + l15]
                    = oacc[rt][ht][r];
    }
    __syncthreads();
    #pragma unroll
    for (int rr = 0; rr < 8; rr++) {
        int row = w * 8 + rr;
        float lt = 0.0f, o = 0.0f;
        #pragma unroll
        for (int wv = 0; wv < 8; wv++) {
            lt += Ls[wv * 64 + row];
            o  += Osf[(wv * 64 + row) * 66 + lane];
        }
        out[kbase + (size_t)(q0 + row) * H_ + lane] = o * (1.0f / lt);
    }
}

extern "C" void kernel_launch(void* const* d_in, const int* in_sizes, int n_in,
                              void* d_out, int out_size, void* d_ws, size_t ws_size,
                              hipStream_t stream) {
    const float* x  = (const float*)d_in[0];
    const float* Wk = (const float*)d_in[1];
    const float* Wq = (const float*)d_in[2];
    const float* Wv = (const float*)d_in[3];

    unsigned short* kb  = (unsigned short*)d_ws;               // 2 MB
    unsigned short* qbf = kb  + (size_t)B_ * T_ * H_;          // 2 MB
    unsigned short* vtb = qbf + (size_t)B_ * T_ * H_;          // 2 MB
    unsigned short* Wt  = (unsigned short*)d_out;              // 384 KB scratch

    wconv<<<48,  256, 0, stream>>>(Wk, Wq, Wv, Wt);
    qkv  <<<512, 512, 0, stream>>>(x, Wt, kb, qbf, vtb);
    attn <<<256, 512, 0, stream>>>(qbf, kb, vtb, (float*)d_out);
}

// Round 15
// 140.780 us; speedup vs baseline: 1.2904x; 1.0126x over previous
//
#include <hip/hip_runtime.h>
#include <stdint.h>

// Head: x[8,2048,1024] fp32; Wk/Wq/Wv [1024,64] fp32 -> out [8,2048,64] fp32
// R19: qkv = R13 geometry with ONE change: wait-before-prefetch ordering.
// R13/R4/R15 issue prefetch(i+1) then __syncthreads -> vmcnt(0) drains the
// JUST-ISSUED stages at age ~0 -> full ~900cyc latency exposed every chunk
// x16 = the invariant 40us (compute ~400cyc/chunk). R14's counted-vmcnt
// test was confounded (also moved to 128KB/1blk/CU). Minimal fix: per
// chunk {asm vmcnt(0) [exact: only chunk-i's 4 own stages outstanding,
// issued one full chunk ago] -> raw s_barrier [all waves' chunk-i stages
// done; buf cb^1 readers retired] -> issue prefetch i+1 -> reads+MFMA}.
// Just-issued stages are never drained; chunk-i stages get a full chunk
// of cover. attn = R18 verbatim (64-row q-tiles, 142.56us total, best).

#define B_ 8
#define T_ 2048
#define C_ 1024
#define H_ 64

typedef float f32x4 __attribute__((ext_vector_type(4)));
typedef short s16x8 __attribute__((ext_vector_type(8)));

__device__ __forceinline__ unsigned int rhu16(float f) {
    return (__float_as_uint(f) + 0x8000u) >> 16;
}
__device__ __forceinline__ unsigned int pkbf(float lo, float hi) {
    unsigned int a = __float_as_uint(lo) + 0x8000u;
    unsigned int b = __float_as_uint(hi) + 0x8000u;
    return __builtin_amdgcn_perm(b, a, 0x07060302u);   // bytes [b3 b2 a3 a2]
}
// async global->LDS, 16B per lane; LDS dest = wave-uniform base + lane*16
__device__ __forceinline__ void ld_lds16(const void* g, void* l) {
    __builtin_amdgcn_global_load_lds(
        (const __attribute__((address_space(1))) unsigned int*)g,
        (__attribute__((address_space(3))) unsigned int*)l, 16, 0, 0);
}

// ---------------------------------------------------------------------------
// K0: 48 blocks = 3 mats x 16 c-groups of 64. Coalesced read, LDS transpose
// (stride 65), coalesced bf16 write. Wq pre-scaled by 1/32 (C^-0.5).
// ---------------------------------------------------------------------------
__global__ __launch_bounds__(256) void wconv(const float* __restrict__ Wk,
        const float* __restrict__ Wq, const float* __restrict__ Wv,
        unsigned short* __restrict__ Wt) {
    __shared__ float ls[64 * 65];
    const int bx = blockIdx.x, t = threadIdx.x;
    const int mat = bx >> 4, c0 = (bx & 15) << 6;
    const float* W = (mat == 0) ? Wk : ((mat == 1) ? Wq : Wv);
    const float sc = (mat == 1) ? 0.03125f : 1.0f;
    #pragma unroll
    for (int k = 0; k < 4; k++) {
        int i = t + (k << 8);
        int cr = i >> 4, hq = (i & 15) << 2;
        float4 v = *reinterpret_cast<const float4*>(&W[(size_t)(c0 + cr) * H_ + hq]);
        ls[cr * 65 + hq + 0] = v.x; ls[cr * 65 + hq + 1] = v.y;
        ls[cr * 65 + hq + 2] = v.z; ls[cr * 65 + hq + 3] = v.w;
    }
    __syncthreads();
    #pragma unroll
    for (int k = 0; k < 4; k++) {
        int i = t + (k << 8);
        int h = i >> 4, cq = (i & 15) << 2;
        float a = ls[(cq + 0) * 65 + h] * sc, b = ls[(cq + 1) * 65 + h] * sc;
        float c = ls[(cq + 2) * 65 + h] * sc, d = ls[(cq + 3) * 65 + h] * sc;
        uint2 o; o.x = pkbf(a, b); o.y = pkbf(c, d);
        *reinterpret_cast<uint2*>(&Wt[(size_t)(mat * 64 + h) * C_ + c0 + cq]) = o;
    }
}

// ---------------------------------------------------------------------------
// K1: QKV projection — R13 geometry, wait-before-prefetch sync. 512 blocks
// x 512 thr; block = 32 rows x 192 cols; wave (wr=w>>2, colb=(w&3)*48)
// owns 16 rows x 48 cols. Per 64-k chunk per wave: {vmcnt(0); s_barrier;
// 4 stage-instrs for chunk i+1; 10 ds_reads; pack; 6 MFMA}. LDS dbuf 64KB,
// 2 blocks/CU, 4 waves/SIMD.
// ---------------------------------------------------------------------------
__global__ __launch_bounds__(512) __attribute__((amdgpu_waves_per_eu(4, 4)))
void qkv(const float* __restrict__ x,
        const unsigned short* __restrict__ Wt,
        unsigned short* __restrict__ kb, unsigned short* __restrict__ qb,
        unsigned short* __restrict__ vtb) {
    __shared__ __align__(16) char smem[65536];   // xbuf 2x8192 | wbuf 2x24576
    char* xb = smem;
    char* wb = smem + 16384;

    const int t = threadIdx.x, lane = t & 63, w = t >> 6;   // w in 0..7
    const int l15 = lane & 15, quad = lane >> 4;
    const int bx = blockIdx.x;
    const int bb = bx >> 6;                 // batch
    const int mt = bx & 63;                 // 32-row tile within batch
    const int m0 = bb * T_ + mt * 32;
    const int wr = w >> 2;                  // row-half of the 32-row tile
    const int colb = (w & 3) * 48;          // 48-col strip

    size_t xg; int xl;
    {
        int rg = w >> 2, j = w & 3;
        xg = (size_t)(m0 + rg * 16 + l15) * C_ + j * 16 + quad * 4;
        xl = w * 1024 + lane * 16;
    }
    size_t wg[3]; int wl[3];
    #pragma unroll
    for (int n = 0; n < 3; n++) {
        int g = w * 3 + n;
        wg[n] = (size_t)(g * 8 + (lane & 7)) * C_ + (lane >> 3) * 8;
        wl[n] = g * 1024 + lane * 16;
    }

    // prologue: stage chunk 0 (uncovered one-time latency, drained at i=0)
    ld_lds16(x + xg, xb + xl);
    #pragma unroll
    for (int n = 0; n < 3; n++) ld_lds16(Wt + wg[n], wb + wl[n]);

    f32x4 acc[3];
    #pragma unroll
    for (int ct = 0; ct < 3; ct++)
        #pragma unroll
        for (int j = 0; j < 4; j++) acc[ct][j] = 0.0f;

    #pragma unroll
    for (int i = 0; i < 16; i++) {
        const int cb = i & 1;

        // exact own-wave wait: ONLY chunk-i's 4 stages are outstanding
        // (chunk i+1 not yet issued) — they were issued one chunk ago.
        asm volatile("s_waitcnt vmcnt(0)" ::: "memory");
        __builtin_amdgcn_sched_barrier(0);
        // all waves' chunk-i stages complete; buf cb^1's chunk-(i-1)
        // readers retired (ds_read results consumed pre-barrier).
        __builtin_amdgcn_s_barrier();
        __builtin_amdgcn_sched_barrier(0);

        // issue prefetch chunk i+1 NOW (never drained; full-chunk cover)
        if (i < 15) {
            const int c1 = (i + 1) * 64;
            char* xn = xb + (cb ^ 1) * 8192;
            char* wn = wb + (cb ^ 1) * 24576;
            ld_lds16(x + xg + c1, xn + xl);
            #pragma unroll
            for (int n = 0; n < 3; n++) ld_lds16(Wt + wg[n] + c1, wn + wl[n]);
        }
        __builtin_amdgcn_sched_barrier(0);

        const float* xc = (const float*)(xb + cb * 8192);
        const unsigned short* wcp = (const unsigned short*)(wb + cb * 24576);

        // frag reads from LDS (chunk i resident)
        float4 xr[2][2];
        #pragma unroll
        for (int ks = 0; ks < 2; ks++)
            #pragma unroll
            for (int h = 0; h < 2; h++) {
                int c = ks * 32 + quad * 8 + h * 4;
                int j = c >> 4, u = (c & 15) >> 2;
                xr[ks][h] = *reinterpret_cast<const float4*>(
                    xc + (wr * 4 + j) * 256 + u * 64 + l15 * 4);
            }
        s16x8 wfr[3][2];
        #pragma unroll
        for (int ct = 0; ct < 3; ct++)
            #pragma unroll
            for (int ks = 0; ks < 2; ks++) {
                int col = colb + ct * 16 + l15;
                wfr[ct][ks] = *reinterpret_cast<const s16x8*>(
                    wcp + (col >> 3) * 512 + ((4 * ks + quad) * 8 + (col & 7)) * 8);
            }

        // pack fp32 -> bf16 A-frags and MFMA
        s16x8 af[2];
        #pragma unroll
        for (int ks = 0; ks < 2; ks++) {
            const float4 a = xr[ks][0], b = xr[ks][1];
            uint4 pk;
            pk.x = pkbf(a.x, a.y); pk.y = pkbf(a.z, a.w);
            pk.z = pkbf(b.x, b.y); pk.w = pkbf(b.z, b.w);
            af[ks] = *reinterpret_cast<s16x8*>(&pk);
        }
        #pragma unroll
        for (int ks = 0; ks < 2; ks++)
            #pragma unroll
            for (int ct = 0; ct < 3; ct++)
                acc[ct] = __builtin_amdgcn_mfma_f32_16x16x32_bf16(
                    af[ks], wfr[ct][ks], acc[ct], 0, 0, 0);
    }

    // epilogue: C row = quad*4+reg (within wave's 16-row strip), col = l15
    #pragma unroll
    for (int ct = 0; ct < 3; ct++) {
        int cbv = colb + ct * 16;
        int sel = cbv >> 6;                 // 0=K 1=Q 2=V, wave-uniform
        int h = (cbv & 63) + l15;
        int row0 = m0 + wr * 16 + quad * 4;
        if (sel < 2) {
            unsigned short* dst = sel ? qb : kb;
            #pragma unroll
            for (int r = 0; r < 4; r++)
                dst[(size_t)(row0 + r) * H_ + h] = (unsigned short)rhu16(acc[ct][r]);
        } else {
            int tt = row0 - bb * T_;        // V transposed: 4 consecutive t
            uint2 pk;
            pk.x = pkbf(acc[ct][0], acc[ct][1]);
            pk.y = pkbf(acc[ct][2], acc[ct][3]);
            *reinterpret_cast<uint2*>(&vtb[((size_t)bb * H_ + h) * T_ + tt]) = pk;
        }
    }
}

// ---------------------------------------------------------------------------
// K2: attention — R18 verbatim (64-row q-tiles, 8 waves; total 142.56us).
// 256 blocks = (batch &7, 64-row q-tile); wave owns a 256-s eighth in 4
// chunks of 64 s. Per iteration: 16 direct register loads, 64 MFMA, 64
// exps/lane. LDS: Pw per wave (64x72 shorts); all-8-wave combine epilogue.
// ---------------------------------------------------------------------------
__global__ __launch_bounds__(512) __attribute__((amdgpu_waves_per_eu(2, 2)))
void attn(
        const unsigned short* __restrict__ qb,
        const unsigned short* __restrict__ kb,
        const unsigned short* __restrict__ vtb,
        float* __restrict__ out) {
    __shared__ __align__(16) char smem[137216];
    // main loop: Pw per wave at smem + w*9216 (64 rows x 72 shorts = 73728B)
    // epilogue (after syncthreads): Osf[8][64][66] f32 (135168B) + Ls[8][64]

    const int t = threadIdx.x, lane = t & 63, w = t >> 6;   // w in 0..7
    const int l15 = lane & 15, quad = lane >> 4;
    const int bb = blockIdx.x & 7;
    const int q0 = (blockIdx.x >> 3) << 6;  // 64-row q tile
    const size_t kbase = (size_t)bb * T_ * H_;
    unsigned short* Pw = (unsigned short*)(smem + w * 9216);

    // Q B-frags (pre-scaled by 1/32 via Wq), kept in regs for all iterations
    s16x8 qf[4][2];
    #pragma unroll
    for (int rt = 0; rt < 4; rt++)
        #pragma unroll
        for (int ks = 0; ks < 2; ks++)
            qf[rt][ks] = *reinterpret_cast<const s16x8*>(
                &qb[kbase + (size_t)(q0 + rt * 16 + l15) * H_ + ks * 32 + quad * 8]);

    const int sw = w << 8;                 // this wave's 256-s eighth base
    const unsigned short* kq = kb + kbase + (size_t)(sw + l15) * H_ + quad * 8;
    const unsigned short* vq[4];
    #pragma unroll
    for (int ht = 0; ht < 4; ht++)
        vq[ht] = vtb + ((size_t)bb * H_ + ht * 16 + l15) * T_ + sw + quad * 8;

    f32x4 oacc[4][4];
    #pragma unroll
    for (int rt = 0; rt < 4; rt++)
        #pragma unroll
        for (int ht = 0; ht < 4; ht++)
            #pragma unroll
            for (int j = 0; j < 4; j++) oacc[rt][ht][j] = 0.0f;
    float l_run[4] = {0.0f, 0.0f, 0.0f, 0.0f};
    const f32x4 z4 = {0.0f, 0.0f, 0.0f, 0.0f};

    for (int it = 0; it < 4; it++) {
        // 16 loads issued back-to-back: 8 K-frags then 8 V-frags. Compiler
        // waits per-use: S-MFMA waits only K; V stays in flight until O-MFMA.
        s16x8 kf[4][2], vf[2][4];
        #pragma unroll
        for (int st = 0; st < 4; st++)
            #pragma unroll
            for (int ks = 0; ks < 2; ks++)
                kf[st][ks] = *reinterpret_cast<const s16x8*>(
                    kq + (size_t)(it * 64 + st * 16) * H_ + ks * 32);
        #pragma unroll
        for (int ks2 = 0; ks2 < 2; ks2++)
            #pragma unroll
            for (int ht = 0; ht < 4; ht++)
                vf[ks2][ht] = *reinterpret_cast<const s16x8*>(
                    vq[ht] + it * 64 + ks2 * 32);

        // S^T = K.Q^T per 16-q group rt (sacc transient: 16 VGPR), then
        // exp (scores bounded; no max-sub) + packed P write (stride 72)
        #pragma unroll
        for (int rt = 0; rt < 4; rt++) {
            f32x4 sacc[4];
            #pragma unroll
            for (int st = 0; st < 4; st++) {
                f32x4 s0v = __builtin_amdgcn_mfma_f32_16x16x32_bf16(
                    kf[st][0], qf[rt][0], z4, 0, 0, 0);
                sacc[st] = __builtin_amdgcn_mfma_f32_16x16x32_bf16(
                    kf[st][1], qf[rt][1], s0v, 0, 0, 0);
            }
            float ls = 0.0f;
            #pragma unroll
            for (int st = 0; st < 4; st++) {
                float p0 = __expf(sacc[st][0]);
                float p1 = __expf(sacc[st][1]);
                float p2 = __expf(sacc[st][2]);
                float p3 = __expf(sacc[st][3]);
                ls += (p0 + p1) + (p2 + p3);
                uint2 pk; pk.x = pkbf(p0, p1); pk.y = pkbf(p2, p3);
                *reinterpret_cast<uint2*>(
                    &Pw[(rt * 16 + l15) * 72 + st * 16 + quad * 4]) = pk;
            }
            l_run[rt] += ls;
        }

        // O += P.V : two 32-s k-steps; P read same-wave LDS (lgkmcnt only)
        #pragma unroll
        for (int rt = 0; rt < 4; rt++)
            #pragma unroll
            for (int ks2 = 0; ks2 < 2; ks2++) {
                s16x8 pf = *reinterpret_cast<const s16x8*>(
                    &Pw[(rt * 16 + l15) * 72 + ks2 * 32 + quad * 8]);
                #pragma unroll
                for (int ht = 0; ht < 4; ht++)
                    oacc[rt][ht] = __builtin_amdgcn_mfma_f32_16x16x32_bf16(
                        pf, vf[ks2][ht], oacc[rt][ht], 0, 0, 0);
            }
    }

    // l: each lane's partial covers its s-eighth rows for q=l15
    #pragma unroll
    for (int rt = 0; rt < 4; rt++) {
        l_run[rt] += __shfl_xor(l_run[rt], 16);
        l_run[rt] += __shfl_xor(l_run[rt], 32);
    }

    // 8-way split-KV combine: ALL waves write partials, then each wave
    // combines 8 rows (lane = h, coalesced output).
    __syncthreads();                       // Pw reads done; safe to overwrite
    float* Osf = (float*)smem;             // [8][64][66]
    float* Ls  = (float*)smem + 8 * 64 * 66;   // [8][64]
    #pragma unroll
    for (int rt = 0; rt < 4; rt++) {
        if (quad == 0) Ls[w * 64 + rt * 16 + l15] = l_run[rt];
        #pragma unroll
        for (int ht = 0; ht < 4; ht++)
            #pragma unroll
            for (int r = 0; r < 4; r++)
                Osf[(w * 64 + rt * 16 + quad * 4 + r) * 66 + ht * 16 + l15]
                    = oacc[rt][ht][r];
    }
    __syncthreads();
    #pragma unroll
    for (int rr = 0; rr < 8; rr++) {
        int row = w * 8 + rr;
        float lt = 0.0f, o = 0.0f;
        #pragma unroll
        for (int wv = 0; wv < 8; wv++) {
            lt += Ls[wv * 64 + row];
            o  += Osf[(wv * 64 + row) * 66 + lane];
        }
        out[kbase + (size_t)(q0 + row) * H_ + lane] = o * (1.0f / lt);
    }
}

extern "C" void kernel_launch(void* const* d_in, const int* in_sizes, int n_in,
                              void* d_out, int out_size, void* d_ws, size_t ws_size,
                              hipStream_t stream) {
    const float* x  = (const float*)d_in[0];
    const float* Wk = (const float*)d_in[1];
    const float* Wq = (const float*)d_in[2];
    const float* Wv = (const float*)d_in[3];

    unsigned short* kb  = (unsigned short*)d_ws;               // 2 MB
    unsigned short* qbf = kb  + (size_t)B_ * T_ * H_;          // 2 MB
    unsigned short* vtb = qbf + (size_t)B_ * T_ * H_;          // 2 MB
    unsigned short* Wt  = (unsigned short*)d_out;              // 384 KB scratch

    wconv<<<48,  256, 0, stream>>>(Wk, Wq, Wv, Wt);
    qkv  <<<512, 512, 0, stream>>>(x, Wt, kb, qbf, vtb);
    attn <<<256, 512, 0, stream>>>(qbf, kb, vtb, (float*)d_out);
}

// Round 19
// 136.692 us; speedup vs baseline: 1.3290x; 1.0299x over previous
//
#include <hip/hip_runtime.h>
#include <stdint.h>

// Head: x[8,2048,1024] fp32; Wk/Wq/Wv [1024,64] fp32 -> out [8,2048,64] fp32
// R21 (2nd resubmit — R17/R18 benches were acquisition timeouts, no data).
// = R20 with the Kt/Qt epilogue stride bug fixed. R20 failed absmax
// 6.7e-2: Kt/Qt cell = 16 lanes x 8 shorts = 128 shorts, so within-cell
// addr must be (s&15)*8 + (h&7); R20 wrote (s&15)*16 -> each cell's upper
// half bled into the neighbor (and past kb into qb). V layout re-audited:
// write/read both expand to (bb*4+h_hi)*32768 + (t>>3)*128 + (h&15)*8 +
// (t&7) — consistent. K/Q read side unchanged (lane*8 ≡ quad*128+l15*8
// matches hseg*128). Layout intent: every attn frag load = SGPR-uniform
// base + lane*16 over CONTIGUOUS 1KB (8 full-line transactions, no
// half-line gather, no overfetch). Frag register contents bit-identical
// to R18/R19. qkv sync = R19 (wait-before-prefetch). attn structure =
// R18 (64-row q-tiles, 8 waves). wconv unchanged.

#define B_ 8
#define T_ 2048
#define C_ 1024
#define H_ 64

typedef float f32x4 __attribute__((ext_vector_type(4)));
typedef short s16x8 __attribute__((ext_vector_type(8)));

__device__ __forceinline__ unsigned int rhu16(float f) {
    return (__float_as_uint(f) + 0x8000u) >> 16;
}
__device__ __forceinline__ unsigned int pkbf(float lo, float hi) {
    unsigned int a = __float_as_uint(lo) + 0x8000u;
    unsigned int b = __float_as_uint(hi) + 0x8000u;
    return __builtin_amdgcn_perm(b, a, 0x07060302u);   // bytes [b3 b2 a3 a2]
}
// async global->LDS, 16B per lane; LDS dest = wave-uniform base + lane*16
__device__ __forceinline__ void ld_lds16(const void* g, void* l) {
    __builtin_amdgcn_global_load_lds(
        (const __attribute__((address_space(1))) unsigned int*)g,
        (__attribute__((address_space(3))) unsigned int*)l, 16, 0, 0);
}

// ---------------------------------------------------------------------------
// K0: 48 blocks = 3 mats x 16 c-groups of 64. Coalesced read, LDS transpose
// (stride 65), coalesced bf16 write. Wq pre-scaled by 1/32 (C^-0.5).
// ---------------------------------------------------------------------------
__global__ __launch_bounds__(256) void wconv(const float* __restrict__ Wk,
        const float* __restrict__ Wq, const float* __restrict__ Wv,
        unsigned short* __restrict__ Wt) {
    __shared__ float ls[64 * 65];
    const int bx = blockIdx.x, t = threadIdx.x;
    const int mat = bx >> 4, c0 = (bx & 15) << 6;
    const float* W = (mat == 0) ? Wk : ((mat == 1) ? Wq : Wv);
    const float sc = (mat == 1) ? 0.03125f : 1.0f;
    #pragma unroll
    for (int k = 0; k < 4; k++) {
        int i = t + (k << 8);
        int cr = i >> 4, hq = (i & 15) << 2;
        float4 v = *reinterpret_cast<const float4*>(&W[(size_t)(c0 + cr) * H_ + hq]);
        ls[cr * 65 + hq + 0] = v.x; ls[cr * 65 + hq + 1] = v.y;
        ls[cr * 65 + hq + 2] = v.z; ls[cr * 65 + hq + 3] = v.w;
    }
    __syncthreads();
    #pragma unroll
    for (int k = 0; k < 4; k++) {
        int i = t + (k << 8);
        int h = i >> 4, cq = (i & 15) << 2;
        float a = ls[(cq + 0) * 65 + h] * sc, b = ls[(cq + 1) * 65 + h] * sc;
        float c = ls[(cq + 2) * 65 + h] * sc, d = ls[(cq + 3) * 65 + h] * sc;
        uint2 o; o.x = pkbf(a, b); o.y = pkbf(c, d);
        *reinterpret_cast<uint2*>(&Wt[(size_t)(mat * 64 + h) * C_ + c0 + cq]) = o;
    }
}

// ---------------------------------------------------------------------------
// K1: QKV projection — R19 sync (wait-before-prefetch), epilogue writes
// TILED layouts. 512 blocks x 512 thr; block = 32 rows x 192 cols.
// Kt/Qt flat shorts: (bb*128 + s>>4)*1024 + (h>>3)*128 + (s&15)*8 + (h&7).
// Vt  flat shorts: (bb*4 + h>>4)*32768 + (t>>3)*128 + (h&15)*8 + (t&7).
// ---------------------------------------------------------------------------
__global__ __launch_bounds__(512) __attribute__((amdgpu_waves_per_eu(4, 4)))
void qkv(const float* __restrict__ x,
        const unsigned short* __restrict__ Wt,
        unsigned short* __restrict__ kb, unsigned short* __restrict__ qb,
        unsigned short* __restrict__ vtb) {
    __shared__ __align__(16) char smem[65536];   // xbuf 2x8192 | wbuf 2x24576
    char* xb = smem;
    char* wb = smem + 16384;

    const int t = threadIdx.x, lane = t & 63, w = t >> 6;   // w in 0..7
    const int l15 = lane & 15, quad = lane >> 4;
    const int bx = blockIdx.x;
    const int bb = bx >> 6;                 // batch
    const int mt = bx & 63;                 // 32-row tile within batch
    const int m0 = bb * T_ + mt * 32;
    const int wr = w >> 2;                  // row-half of the 32-row tile
    const int colb = (w & 3) * 48;          // 48-col strip

    size_t xg; int xl;
    {
        int rg = w >> 2, j = w & 3;
        xg = (size_t)(m0 + rg * 16 + l15) * C_ + j * 16 + quad * 4;
        xl = w * 1024 + lane * 16;
    }
    size_t wg[3]; int wl[3];
    #pragma unroll
    for (int n = 0; n < 3; n++) {
        int g = w * 3 + n;
        wg[n] = (size_t)(g * 8 + (lane & 7)) * C_ + (lane >> 3) * 8;
        wl[n] = g * 1024 + lane * 16;
    }

    // prologue: stage chunk 0 (uncovered one-time latency, drained at i=0)
    ld_lds16(x + xg, xb + xl);
    #pragma unroll
    for (int n = 0; n < 3; n++) ld_lds16(Wt + wg[n], wb + wl[n]);

    f32x4 acc[3];
    #pragma unroll
    for (int ct = 0; ct < 3; ct++)
        #pragma unroll
        for (int j = 0; j < 4; j++) acc[ct][j] = 0.0f;

    #pragma unroll
    for (int i = 0; i < 16; i++) {
        const int cb = i & 1;

        // exact own-wave wait: ONLY chunk-i's 4 stages are outstanding.
        asm volatile("s_waitcnt vmcnt(0)" ::: "memory");
        __builtin_amdgcn_sched_barrier(0);
        __builtin_amdgcn_s_barrier();
        __builtin_amdgcn_sched_barrier(0);

        // issue prefetch chunk i+1 NOW (never drained; full-chunk cover)
        if (i < 15) {
            const int c1 = (i + 1) * 64;
            char* xn = xb + (cb ^ 1) * 8192;
            char* wn = wb + (cb ^ 1) * 24576;
            ld_lds16(x + xg + c1, xn + xl);
            #pragma unroll
            for (int n = 0; n < 3; n++) ld_lds16(Wt + wg[n] + c1, wn + wl[n]);
        }
        __builtin_amdgcn_sched_barrier(0);

        const float* xc = (const float*)(xb + cb * 8192);
        const unsigned short* wcp = (const unsigned short*)(wb + cb * 24576);

        float4 xr[2][2];
        #pragma unroll
        for (int ks = 0; ks < 2; ks++)
            #pragma unroll
            for (int h = 0; h < 2; h++) {
                int c = ks * 32 + quad * 8 + h * 4;
                int j = c >> 4, u = (c & 15) >> 2;
                xr[ks][h] = *reinterpret_cast<const float4*>(
                    xc + (wr * 4 + j) * 256 + u * 64 + l15 * 4);
            }
        s16x8 wfr[3][2];
        #pragma unroll
        for (int ct = 0; ct < 3; ct++)
            #pragma unroll
            for (int ks = 0; ks < 2; ks++) {
                int col = colb + ct * 16 + l15;
                wfr[ct][ks] = *reinterpret_cast<const s16x8*>(
                    wcp + (col >> 3) * 512 + ((4 * ks + quad) * 8 + (col & 7)) * 8);
            }

        s16x8 af[2];
        #pragma unroll
        for (int ks = 0; ks < 2; ks++) {
            const float4 a = xr[ks][0], b = xr[ks][1];
            uint4 pk;
            pk.x = pkbf(a.x, a.y); pk.y = pkbf(a.z, a.w);
            pk.z = pkbf(b.x, b.y); pk.w = pkbf(b.z, b.w);
            af[ks] = *reinterpret_cast<s16x8*>(&pk);
        }
        #pragma unroll
        for (int ks = 0; ks < 2; ks++)
            #pragma unroll
            for (int ct = 0; ct < 3; ct++)
                acc[ct] = __builtin_amdgcn_mfma_f32_16x16x32_bf16(
                    af[ks], wfr[ct][ks], acc[ct], 0, 0, 0);
    }

    // epilogue: acc row = s = mt*32 + wr*16 + quad*4 + r; col h = hb + l15
    #pragma unroll
    for (int ct = 0; ct < 3; ct++) {
        int cbv = colb + ct * 16;
        int sel = cbv >> 6;                 // 0=K 1=Q 2=V, wave-uniform
        int hb = cbv & 63;                  // multiple of 16
        int h = hb + l15;
        if (sel < 2) {
            unsigned short* dst = sel ? qb : kb;
            // Kt/Qt: (bb*128 + s>>4)*1024 + (h>>3)*128 + (s&15)*8 + (h&7)
            // here s>>4 = mt*2 + wr, s&15 = quad*4 + r
            size_t base = ((size_t)(bb * 128 + mt * 2 + wr) * 8 + (h >> 3)) * 128
                        + (quad * 4) * 8 + (h & 7);
            #pragma unroll
            for (int r = 0; r < 4; r++)
                dst[base + r * 8] = (unsigned short)rhu16(acc[ct][r]);
        } else {
            // Vt: (bb*4 + h>>4)*32768 + (t>>3)*128 + (h&15)*8 + (t&7)
            // t = mt*32 + wr*16 + quad*4 + r; t>>3 = mt*4+wr*2+(quad>>1)
            int thi = mt * 4 + wr * 2 + (quad >> 1);
            size_t base = ((size_t)(bb * 4 + (h >> 4)) * 256 + thi) * 128
                        + (h & 15) * 8 + (quad & 1) * 4;
            uint2 pk;
            pk.x = pkbf(acc[ct][0], acc[ct][1]);
            pk.y = pkbf(acc[ct][2], acc[ct][3]);
            *reinterpret_cast<uint2*>(&vtb[base]) = pk;
        }
    }
}

// ---------------------------------------------------------------------------
// K2: attention — R18 structure (64-row q-tiles, 8 waves, 256 blocks) with
// TILED fully-coalesced loads: every frag load = SGPR-uniform base +
// lane*16 over contiguous 1KB (8 full-line transactions, no overfetch).
// Fragment register contents identical to R18. Combine epilogue unchanged.
// ---------------------------------------------------------------------------
__global__ __launch_bounds__(512) __attribute__((amdgpu_waves_per_eu(2, 2)))
void attn(
        const unsigned short* __restrict__ qb,
        const unsigned short* __restrict__ kb,
        const unsigned short* __restrict__ vtb,
        float* __restrict__ out) {
    __shared__ __align__(16) char smem[137216];
    // main loop: Pw per wave at smem + w*9216 (64 rows x 72 shorts = 73728B)
    // epilogue (after syncthreads): Osf[8][64][66] f32 (135168B) + Ls[8][64]

    const int t = threadIdx.x, lane = t & 63, w = t >> 6;   // w in 0..7
    const int l15 = lane & 15, quad = lane >> 4;
    const int bb = blockIdx.x & 7;
    const int qt = blockIdx.x >> 3;         // 64-row q tile index
    const int q0 = qt << 6;
    const size_t kbase = (size_t)bb * T_ * H_;
    unsigned short* Pw = (unsigned short*)(smem + w * 9216);

    // tiled-layout base pointers (all offsets below are compile-time)
    const unsigned short* Qb = qb  + ((size_t)(bb * 128 + qt * 4) * 1024) + lane * 8;
    const unsigned short* Kb = kb  + ((size_t)(bb * 128 + w * 16) * 1024) + lane * 8;
    const unsigned short* Vb = vtb + ((size_t)(bb * 4) * 256 + w * 32) * 128 + lane * 8;

    // Q B-frags (pre-scaled by 1/32 via Wq), kept in regs for all iterations
    s16x8 qf[4][2];
    #pragma unroll
    for (int rt = 0; rt < 4; rt++)
        #pragma unroll
        for (int ks = 0; ks < 2; ks++)
            qf[rt][ks] = *reinterpret_cast<const s16x8*>(Qb + rt * 1024 + ks * 512);

    f32x4 oacc[4][4];
    #pragma unroll
    for (int rt = 0; rt < 4; rt++)
        #pragma unroll
        for (int ht = 0; ht < 4; ht++)
            #pragma unroll
            for (int j = 0; j < 4; j++) oacc[rt][ht][j] = 0.0f;
    float l_run[4] = {0.0f, 0.0f, 0.0f, 0.0f};
    const f32x4 z4 = {0.0f, 0.0f, 0.0f, 0.0f};

    for (int it = 0; it < 4; it++) {
        // 16 fully-coalesced loads: 8 K-frags then 8 V-frags.
        s16x8 kf[4][2], vf[2][4];
        #pragma unroll
        for (int st = 0; st < 4; st++)
            #pragma unroll
            for (int ks = 0; ks < 2; ks++)
                kf[st][ks] = *reinterpret_cast<const s16x8*>(
                    Kb + (it * 4 + st) * 1024 + ks * 512);
        #pragma unroll
        for (int ks2 = 0; ks2 < 2; ks2++)
            #pragma unroll
            for (int ht = 0; ht < 4; ht++)
                vf[ks2][ht] = *reinterpret_cast<const s16x8*>(
                    Vb + ht * 32768 + it * 1024 + ks2 * 512);

        // S^T = K.Q^T per 16-q group rt (sacc transient: 16 VGPR), then
        // exp (scores bounded; no max-sub) + packed P write (stride 72)
        #pragma unroll
        for (int rt = 0; rt < 4; rt++) {
            f32x4 sacc[4];
            #pragma unroll
            for (int st = 0; st < 4; st++) {
                f32x4 s0v = __builtin_amdgcn_mfma_f32_16x16x32_bf16(
                    kf[st][0], qf[rt][0], z4, 0, 0, 0);
                sacc[st] = __builtin_amdgcn_mfma_f32_16x16x32_bf16(
                    kf[st][1], qf[rt][1], s0v, 0, 0, 0);
            }
            float ls = 0.0f;
            #pragma unroll
            for (int st = 0; st < 4; st++) {
                float p0 = __expf(sacc[st][0]);
                float p1 = __expf(sacc[st][1]);
                float p2 = __expf(sacc[st][2]);
                float p3 = __expf(sacc[st][3]);
                ls += (p0 + p1) + (p2 + p3);
                uint2 pk; pk.x = pkbf(p0, p1); pk.y = pkbf(p2, p3);
                *reinterpret_cast<uint2*>(
                    &Pw[(rt * 16 + l15) * 72 + st * 16 + quad * 4]) = pk;
            }
            l_run[rt] += ls;
        }

        // O += P.V : two 32-s k-steps; P read same-wave LDS (lgkmcnt only)
        #pragma unroll
        for (int rt = 0; rt < 4; rt++)
            #pragma unroll
            for (int ks2 = 0; ks2 < 2; ks2++) {
                s16x8 pf = *reinterpret_cast<const s16x8*>(
                    &Pw[(rt * 16 + l15) * 72 + ks2 * 32 + quad * 8]);
                #pragma unroll
                for (int ht = 0; ht < 4; ht++)
                    oacc[rt][ht] = __builtin_amdgcn_mfma_f32_16x16x32_bf16(
                        pf, vf[ks2][ht], oacc[rt][ht], 0, 0, 0);
            }
    }

    // l: each lane's partial covers its s-eighth rows for q=l15
    #pragma unroll
    for (int rt = 0; rt < 4; rt++) {
        l_run[rt] += __shfl_xor(l_run[rt], 16);
        l_run[rt] += __shfl_xor(l_run[rt], 32);
    }

    // 8-way split-KV combine: ALL waves write partials, then each wave
    // combines 8 rows (lane = h, coalesced output).
    __syncthreads();                       // Pw reads done; safe to overwrite
    float* Osf = (float*)smem;             // [8][64][66]
    float* Ls  = (float*)smem + 8 * 64 * 66;   // [8][64]
    #pragma unroll
    for (int rt = 0; rt < 4; rt++) {
        if (quad == 0) Ls[w * 64 + rt * 16 + l15] = l_run[rt];
        #pragma unroll
        for (int ht = 0; ht < 4; ht++)
            #pragma unroll
            for (int r = 0; r < 4; r++)
                Osf[(w * 64 + rt * 16 + quad * 4 + r) * 66 + ht * 16 + l15]
                    = oacc[rt][ht][r];
    }
    __syncthreads();
    #pragma unroll
    for (int rr = 0; rr < 8; rr++) {
        int row = w * 8 + rr;
        float lt = 0.0f, o = 0.0f;
        #pragma unroll
        for (int wv = 0; wv < 8; wv++) {
            lt += Ls[wv * 64 + row];
            o  += Osf[(wv * 64 + row) * 66 + lane];
        }
        out[kbase + (size_t)(q0 + row) * H_ + lane] = o * (1.0f / lt);
    }
}

extern "C" void kernel_launch(void* const* d_in, const int* in_sizes, int n_in,
                              void* d_out, int out_size, void* d_ws, size_t ws_size,
                              hipStream_t stream) {
    const float* x  = (const float*)d_in[0];
    const float* Wk = (const float*)d_in[1];
    const float* Wq = (const float*)d_in[2];
    const float* Wv = (const float*)d_in[3];

    unsigned short* kb  = (unsigned short*)d_ws;               // 2 MB
    unsigned short* qbf = kb  + (size_t)B_ * T_ * H_;          // 2 MB
    unsigned short* vtb = qbf + (size_t)B_ * T_ * H_;          // 2 MB
    unsigned short* Wt  = (unsigned short*)d_out;              // 384 KB scratch

    wconv<<<48,  256, 0, stream>>>(Wk, Wq, Wv, Wt);
    qkv  <<<512, 512, 0, stream>>>(x, Wt, kb, qbf, vtb);
    attn <<<256, 512, 0, stream>>>(qbf, kb, vtb, (float*)d_out);
}

// Round 20
// 133.815 us; speedup vs baseline: 1.3576x; 1.0215x over previous
//
#include <hip/hip_runtime.h>
#include <stdint.h>

// Head: x[8,2048,1024] fp32; Wk/Wq/Wv [1024,64] fp32 -> out [8,2048,64] fp32
// R22 = R21 (136.69us best) + full-line x staging in qkv. R21 proved the
// half-line-gather theory on attn (tiled loads: -4.1us); qkv's x-stage has
// the same disease: 16 rows x 64B per instr = 16 half-line txns. New lane
// map: instr id=w stages 4 rows x 256B contiguous (8 full-line txns), with
// G21 both-sides XOR swizzle (linear LDS dest + inverse-swizzled global
// source + same XOR on read): cell' = cell ^ ((row&3)<<1) ^ ((row>>2)&1).
// Verified bijective per row (reads stay contiguous) and stage id = row>>2,
// row&3 = q so stage/read XOR terms match identically. W staging already
// full-line (8 rows x 128B, bank-conflict counter 0). qkv sync = R19
// wait-before-prefetch. attn = R21 (tiled K/Q/V). wconv unchanged.

#define B_ 8
#define T_ 2048
#define C_ 1024
#define H_ 64

typedef float f32x4 __attribute__((ext_vector_type(4)));
typedef short s16x8 __attribute__((ext_vector_type(8)));

__device__ __forceinline__ unsigned int rhu16(float f) {
    return (__float_as_uint(f) + 0x8000u) >> 16;
}
__device__ __forceinline__ unsigned int pkbf(float lo, float hi) {
    unsigned int a = __float_as_uint(lo) + 0x8000u;
    unsigned int b = __float_as_uint(hi) + 0x8000u;
    return __builtin_amdgcn_perm(b, a, 0x07060302u);   // bytes [b3 b2 a3 a2]
}
// async global->LDS, 16B per lane; LDS dest = wave-uniform base + lane*16
__device__ __forceinline__ void ld_lds16(const void* g, void* l) {
    __builtin_amdgcn_global_load_lds(
        (const __attribute__((address_space(1))) unsigned int*)g,
        (__attribute__((address_space(3))) unsigned int*)l, 16, 0, 0);
}

// ---------------------------------------------------------------------------
// K0: 48 blocks = 3 mats x 16 c-groups of 64. Coalesced read, LDS transpose
// (stride 65), coalesced bf16 write. Wq pre-scaled by 1/32 (C^-0.5).
// ---------------------------------------------------------------------------
__global__ __launch_bounds__(256) void wconv(const float* __restrict__ Wk,
        const float* __restrict__ Wq, const float* __restrict__ Wv,
        unsigned short* __restrict__ Wt) {
    __shared__ float ls[64 * 65];
    const int bx = blockIdx.x, t = threadIdx.x;
    const int mat = bx >> 4, c0 = (bx & 15) << 6;
    const float* W = (mat == 0) ? Wk : ((mat == 1) ? Wq : Wv);
    const float sc = (mat == 1) ? 0.03125f : 1.0f;
    #pragma unroll
    for (int k = 0; k < 4; k++) {
        int i = t + (k << 8);
        int cr = i >> 4, hq = (i & 15) << 2;
        float4 v = *reinterpret_cast<const float4*>(&W[(size_t)(c0 + cr) * H_ + hq]);
        ls[cr * 65 + hq + 0] = v.x; ls[cr * 65 + hq + 1] = v.y;
        ls[cr * 65 + hq + 2] = v.z; ls[cr * 65 + hq + 3] = v.w;
    }
    __syncthreads();
    #pragma unroll
    for (int k = 0; k < 4; k++) {
        int i = t + (k << 8);
        int h = i >> 4, cq = (i & 15) << 2;
        float a = ls[(cq + 0) * 65 + h] * sc, b = ls[(cq + 1) * 65 + h] * sc;
        float c = ls[(cq + 2) * 65 + h] * sc, d = ls[(cq + 3) * 65 + h] * sc;
        uint2 o; o.x = pkbf(a, b); o.y = pkbf(c, d);
        *reinterpret_cast<uint2*>(&Wt[(size_t)(mat * 64 + h) * C_ + c0 + cq]) = o;
    }
}

// ---------------------------------------------------------------------------
// K1: QKV projection — R19 sync, tiled output layouts (R21), x staging
// restructured to full-line: instr id=w stages rows w*4..w*4+3, 256B/row
// contiguous (XOR-permuted cell order). LDS x layout (floats):
// (row>>2)*256 + (row&3)*64 + (cell ^ ((row&3)<<1) ^ ((row>>2)&1))*4.
// Kt/Qt flat shorts: (bb*128 + s>>4)*1024 + (h>>3)*128 + (s&15)*8 + (h&7).
// Vt  flat shorts: (bb*4 + h>>4)*32768 + (t>>3)*128 + (h&15)*8 + (t&7).
// ---------------------------------------------------------------------------
__global__ __launch_bounds__(512) __attribute__((amdgpu_waves_per_eu(4, 4)))
void qkv(const float* __restrict__ x,
        const unsigned short* __restrict__ Wt,
        unsigned short* __restrict__ kb, unsigned short* __restrict__ qb,
        unsigned short* __restrict__ vtb) {
    __shared__ __align__(16) char smem[65536];   // xbuf 2x8192 | wbuf 2x24576
    char* xb = smem;
    char* wb = smem + 16384;

    const int t = threadIdx.x, lane = t & 63, w = t >> 6;   // w in 0..7
    const int l15 = lane & 15, quad = lane >> 4;
    const int bx = blockIdx.x;
    const int bb = bx >> 6;                 // batch
    const int mt = bx & 63;                 // 32-row tile within batch
    const int m0 = bb * T_ + mt * 32;
    const int wr = w >> 2;                  // row-half of the 32-row tile
    const int colb = (w & 3) * 48;          // 48-col strip

    // x stage: full-line. lane q=lane>>4 (row within id-group), seg=lane&15.
    // src col cell = seg ^ (q<<1) ^ (w&1)  (inverse swizzle, bijective)
    size_t xg; int xl;
    {
        int q = lane >> 4, seg = lane & 15;
        int cell = seg ^ (q << 1) ^ (w & 1);
        xg = (size_t)(m0 + w * 4 + q) * C_ + cell * 4;
        xl = w * 1024 + lane * 16;
    }
    size_t wg[3]; int wl[3];
    #pragma unroll
    for (int n = 0; n < 3; n++) {
        int g = w * 3 + n;
        wg[n] = (size_t)(g * 8 + (lane & 7)) * C_ + (lane >> 3) * 8;
        wl[n] = g * 1024 + lane * 16;
    }

    // prologue: stage chunk 0 (uncovered one-time latency, drained at i=0)
    ld_lds16(x + xg, xb + xl);
    #pragma unroll
    for (int n = 0; n < 3; n++) ld_lds16(Wt + wg[n], wb + wl[n]);

    f32x4 acc[3];
    #pragma unroll
    for (int ct = 0; ct < 3; ct++)
        #pragma unroll
        for (int j = 0; j < 4; j++) acc[ct][j] = 0.0f;

    #pragma unroll
    for (int i = 0; i < 16; i++) {
        const int cb = i & 1;

        // exact own-wave wait: ONLY chunk-i's 4 stages are outstanding.
        asm volatile("s_waitcnt vmcnt(0)" ::: "memory");
        __builtin_amdgcn_sched_barrier(0);
        __builtin_amdgcn_s_barrier();
        __builtin_amdgcn_sched_barrier(0);

        // issue prefetch chunk i+1 NOW (never drained; full-chunk cover)
        if (i < 15) {
            const int c1 = (i + 1) * 64;
            char* xn = xb + (cb ^ 1) * 8192;
            char* wn = wb + (cb ^ 1) * 24576;
            ld_lds16(x + xg + c1, xn + xl);
            #pragma unroll
            for (int n = 0; n < 3; n++) ld_lds16(Wt + wg[n] + c1, wn + wl[n]);
        }
        __builtin_amdgcn_sched_barrier(0);

        const float* xc = (const float*)(xb + cb * 8192);
        const unsigned short* wcp = (const unsigned short*)(wb + cb * 24576);

        // x frag reads with matching swizzle: row = wr*16+l15,
        // idp = row>>2 = wr*4+(l15>>2), rq = row&3 = l15&3,
        // cell = ks*8 + quad*2 + h, csw = cell ^ (rq<<1) ^ (idp&1)
        float4 xr[2][2];
        #pragma unroll
        for (int ks = 0; ks < 2; ks++)
            #pragma unroll
            for (int h = 0; h < 2; h++) {
                int idp = wr * 4 + (l15 >> 2);
                int rq  = l15 & 3;
                int cell = ks * 8 + quad * 2 + h;
                int csw = cell ^ (rq << 1) ^ (idp & 1);
                xr[ks][h] = *reinterpret_cast<const float4*>(
                    xc + idp * 256 + rq * 64 + csw * 4);
            }
        s16x8 wfr[3][2];
        #pragma unroll
        for (int ct = 0; ct < 3; ct++)
            #pragma unroll
            for (int ks = 0; ks < 2; ks++) {
                int col = colb + ct * 16 + l15;
                wfr[ct][ks] = *reinterpret_cast<const s16x8*>(
                    wcp + (col >> 3) * 512 + ((4 * ks + quad) * 8 + (col & 7)) * 8);
            }

        s16x8 af[2];
        #pragma unroll
        for (int ks = 0; ks < 2; ks++) {
            const float4 a = xr[ks][0], b = xr[ks][1];
            uint4 pk;
            pk.x = pkbf(a.x, a.y); pk.y = pkbf(a.z, a.w);
            pk.z = pkbf(b.x, b.y); pk.w = pkbf(b.z, b.w);
            af[ks] = *reinterpret_cast<s16x8*>(&pk);
        }
        #pragma unroll
        for (int ks = 0; ks < 2; ks++)
            #pragma unroll
            for (int ct = 0; ct < 3; ct++)
                acc[ct] = __builtin_amdgcn_mfma_f32_16x16x32_bf16(
                    af[ks], wfr[ct][ks], acc[ct], 0, 0, 0);
    }

    // epilogue: acc row = s = mt*32 + wr*16 + quad*4 + r; col h = hb + l15
    #pragma unroll
    for (int ct = 0; ct < 3; ct++) {
        int cbv = colb + ct * 16;
        int sel = cbv >> 6;                 // 0=K 1=Q 2=V, wave-uniform
        int hb = cbv & 63;                  // multiple of 16
        int h = hb + l15;
        if (sel < 2) {
            unsigned short* dst = sel ? qb : kb;
            // Kt/Qt: (bb*128 + s>>4)*1024 + (h>>3)*128 + (s&15)*8 + (h&7)
            size_t base = ((size_t)(bb * 128 + mt * 2 + wr) * 8 + (h >> 3)) * 128
                        + (quad * 4) * 8 + (h & 7);
            #pragma unroll
            for (int r = 0; r < 4; r++)
                dst[base + r * 8] = (unsigned short)rhu16(acc[ct][r]);
        } else {
            // Vt: (bb*4 + h>>4)*32768 + (t>>3)*128 + (h&15)*8 + (t&7)
            int thi = mt * 4 + wr * 2 + (quad >> 1);
            size_t base = ((size_t)(bb * 4 + (h >> 4)) * 256 + thi) * 128
                        + (h & 15) * 8 + (quad & 1) * 4;
            uint2 pk;
            pk.x = pkbf(acc[ct][0], acc[ct][1]);
            pk.y = pkbf(acc[ct][2], acc[ct][3]);
            *reinterpret_cast<uint2*>(&vtb[base]) = pk;
        }
    }
}

// ---------------------------------------------------------------------------
// K2: attention — R18 structure (64-row q-tiles, 8 waves, 256 blocks) with
// TILED fully-coalesced loads: every frag load = SGPR-uniform base +
// lane*16 over contiguous 1KB (8 full-line transactions, no overfetch).
// Fragment register contents identical to R18. Combine epilogue unchanged.
// ---------------------------------------------------------------------------
__global__ __launch_bounds__(512) __attribute__((amdgpu_waves_per_eu(2, 2)))
void attn(
        const unsigned short* __restrict__ qb,
        const unsigned short* __restrict__ kb,
        const unsigned short* __restrict__ vtb,
        float* __restrict__ out) {
    __shared__ __align__(16) char smem[137216];
    // main loop: Pw per wave at smem + w*9216 (64 rows x 72 shorts = 73728B)
    // epilogue (after syncthreads): Osf[8][64][66] f32 (135168B) + Ls[8][64]

    const int t = threadIdx.x, lane = t & 63, w = t >> 6;   // w in 0..7
    const int l15 = lane & 15, quad = lane >> 4;
    const int bb = blockIdx.x & 7;
    const int qt = blockIdx.x >> 3;         // 64-row q tile index
    const int q0 = qt << 6;
    const size_t kbase = (size_t)bb * T_ * H_;
    unsigned short* Pw = (unsigned short*)(smem + w * 9216);

    // tiled-layout base pointers (all offsets below are compile-time)
    const unsigned short* Qb = qb  + ((size_t)(bb * 128 + qt * 4) * 1024) + lane * 8;
    const unsigned short* Kb = kb  + ((size_t)(bb * 128 + w * 16) * 1024) + lane * 8;
    const unsigned short* Vb = vtb + ((size_t)(bb * 4) * 256 + w * 32) * 128 + lane * 8;

    // Q B-frags (pre-scaled by 1/32 via Wq), kept in regs for all iterations
    s16x8 qf[4][2];
    #pragma unroll
    for (int rt = 0; rt < 4; rt++)
        #pragma unroll
        for (int ks = 0; ks < 2; ks++)
            qf[rt][ks] = *reinterpret_cast<const s16x8*>(Qb + rt * 1024 + ks * 512);

    f32x4 oacc[4][4];
    #pragma unroll
    for (int rt = 0; rt < 4; rt++)
        #pragma unroll
        for (int ht = 0; ht < 4; ht++)
            #pragma unroll
            for (int j = 0; j < 4; j++) oacc[rt][ht][j] = 0.0f;
    float l_run[4] = {0.0f, 0.0f, 0.0f, 0.0f};
    const f32x4 z4 = {0.0f, 0.0f, 0.0f, 0.0f};

    for (int it = 0; it < 4; it++) {
        // 16 fully-coalesced loads: 8 K-frags then 8 V-frags.
        s16x8 kf[4][2], vf[2][4];
        #pragma unroll
        for (int st = 0; st < 4; st++)
            #pragma unroll
            for (int ks = 0; ks < 2; ks++)
                kf[st][ks] = *reinterpret_cast<const s16x8*>(
                    Kb + (it * 4 + st) * 1024 + ks * 512);
        #pragma unroll
        for (int ks2 = 0; ks2 < 2; ks2++)
            #pragma unroll
            for (int ht = 0; ht < 4; ht++)
                vf[ks2][ht] = *reinterpret_cast<const s16x8*>(
                    Vb + ht * 32768 + it * 1024 + ks2 * 512);

        // S^T = K.Q^T per 16-q group rt (sacc transient: 16 VGPR), then
        // exp (scores bounded; no max-sub) + packed P write (stride 72)
        #pragma unroll
        for (int rt = 0; rt < 4; rt++) {
            f32x4 sacc[4];
            #pragma unroll
            for (int st = 0; st < 4; st++) {
                f32x4 s0v = __builtin_amdgcn_mfma_f32_16x16x32_bf16(
                    kf[st][0], qf[rt][0], z4, 0, 0, 0);
                sacc[st] = __builtin_amdgcn_mfma_f32_16x16x32_bf16(
                    kf[st][1], qf[rt][1], s0v, 0, 0, 0);
            }
            float ls = 0.0f;
            #pragma unroll
            for (int st = 0; st < 4; st++) {
                float p0 = __expf(sacc[st][0]);
                float p1 = __expf(sacc[st][1]);
                float p2 = __expf(sacc[st][2]);
                float p3 = __expf(sacc[st][3]);
                ls += (p0 + p1) + (p2 + p3);
                uint2 pk; pk.x = pkbf(p0, p1); pk.y = pkbf(p2, p3);
                *reinterpret_cast<uint2*>(
                    &Pw[(rt * 16 + l15) * 72 + st * 16 + quad * 4]) = pk;
            }
            l_run[rt] += ls;
        }

        // O += P.V : two 32-s k-steps; P read same-wave LDS (lgkmcnt only)
        #pragma unroll
        for (int rt = 0; rt < 4; rt++)
            #pragma unroll
            for (int ks2 = 0; ks2 < 2; ks2++) {
                s16x8 pf = *reinterpret_cast<const s16x8*>(
                    &Pw[(rt * 16 + l15) * 72 + ks2 * 32 + quad * 8]);
                #pragma unroll
                for (int ht = 0; ht < 4; ht++)
                    oacc[rt][ht] = __builtin_amdgcn_mfma_f32_16x16x32_bf16(
                        pf, vf[ks2][ht], oacc[rt][ht], 0, 0, 0);
            }
    }

    // l: each lane's partial covers its s-eighth rows for q=l15
    #pragma unroll
    for (int rt = 0; rt < 4; rt++) {
        l_run[rt] += __shfl_xor(l_run[rt], 16);
        l_run[rt] += __shfl_xor(l_run[rt], 32);
    }

    // 8-way split-KV combine: ALL waves write partials, then each wave
    // combines 8 rows (lane = h, coalesced output).
    __syncthreads();                       // Pw reads done; safe to overwrite
    float* Osf = (float*)smem;             // [8][64][66]
    float* Ls  = (float*)smem + 8 * 64 * 66;   // [8][64]
    #pragma unroll
    for (int rt = 0; rt < 4; rt++) {
        if (quad == 0) Ls[w * 64 + rt * 16 + l15] = l_run[rt];
        #pragma unroll
        for (int ht = 0; ht < 4; ht++)
            #pragma unroll
            for (int r = 0; r < 4; r++)
                Osf[(w * 64 + rt * 16 + quad * 4 + r) * 66 + ht * 16 + l15]
                    = oacc[rt][ht][r];
    }
    __syncthreads();
    #pragma unroll
    for (int rr = 0; rr < 8; rr++) {
        int row = w * 8 + rr;
        float lt = 0.0f, o = 0.0f;
        #pragma unroll
        for (int wv = 0; wv < 8; wv++) {
            lt += Ls[wv * 64 + row];
            o  += Osf[(wv * 64 + row) * 66 + lane];
        }
        out[kbase + (size_t)(q0 + row) * H_ + lane] = o * (1.0f / lt);
    }
}

extern "C" void kernel_launch(void* const* d_in, const int* in_sizes, int n_in,
                              void* d_out, int out_size, void* d_ws, size_t ws_size,
                              hipStream_t stream) {
    const float* x  = (const float*)d_in[0];
    const float* Wk = (const float*)d_in[1];
    const float* Wq = (const float*)d_in[2];
    const float* Wv = (const float*)d_in[3];

    unsigned short* kb  = (unsigned short*)d_ws;               // 2 MB
    unsigned short* qbf = kb  + (size_t)B_ * T_ * H_;          // 2 MB
    unsigned short* vtb = qbf + (size_t)B_ * T_ * H_;          // 2 MB
    unsigned short* Wt  = (unsigned short*)d_out;              // 384 KB scratch

    wconv<<<48,  256, 0, stream>>>(Wk, Wq, Wv, Wt);
    qkv  <<<512, 512, 0, stream>>>(x, Wt, kb, qbf, vtb);
    attn <<<256, 512, 0, stream>>>(qbf, kb, vtb, (float*)d_out);
}